// Round 3
// baseline (1166.046 us; speedup 1.0000x reference)
//
#include <hip/hip_runtime.h>
#include <hip/hip_bf16.h>
#include <float.h>
#include <math.h>

#define B 32
#define NN 999
#define S 1000
#define D 128
#define F 512
#define L 6
#define EPSN 1e-5f

typedef __attribute__((ext_vector_type(4))) float f32x4;
typedef __attribute__((ext_vector_type(4))) short s16x4;
typedef __attribute__((ext_vector_type(8))) short s16x8;

#if defined(__has_builtin)
#if __has_builtin(__builtin_amdgcn_mfma_f32_16x16x16bf16_1k)
#define HAVE_MFMA16 1
#endif
#if __has_builtin(__builtin_amdgcn_mfma_f32_16x16x32_bf16)
#define HAVE_MFMA32 1
#endif
#endif

#ifdef HAVE_MFMA16
#define MFMA16(a, b, c) __builtin_amdgcn_mfma_f32_16x16x16bf16_1k((a), (b), (c), 0, 0, 0)
#else
static __device__ __forceinline__ f32x4 mfma16_asm(s16x4 a, s16x4 b, f32x4 c) {
    asm volatile("v_mfma_f32_16x16x16_bf16 %0, %1, %2, %0\n\ts_nop 7\n\ts_nop 7"
                 : "+v"(c) : "v"(a), "v"(b));
    return c;
}
#define MFMA16(a, b, c) mfma16_asm((a), (b), (c))
#endif

#ifdef HAVE_MFMA32
#define MFMA32(a, b, c) __builtin_amdgcn_mfma_f32_16x16x32_bf16((a), (b), (c), 0, 0, 0)
#else
static __device__ __forceinline__ f32x4 mfma32_asm(s16x8 a, s16x8 b, f32x4 c) {
    asm volatile("v_mfma_f32_16x16x32_bf16 %0, %1, %2, %0\n\ts_nop 7\n\ts_nop 7"
                 : "+v"(c) : "v"(a), "v"(b));
    return c;
}
#define MFMA32(a, b, c) mfma32_asm((a), (b), (c))
#endif

__device__ __forceinline__ float n2n(float v) {
    if (v != v) return 0.f;
    if (isinf(v)) return v > 0.f ? FLT_MAX : -FLT_MAX;
    return v;
}

__device__ __forceinline__ unsigned short f2bf(float x) {
    unsigned u = __float_as_uint(x);
    return (unsigned short)((u + 0x7fffu + ((u >> 16) & 1u)) >> 16);
}

__device__ __forceinline__ float bf2f(unsigned short v) {
    return __uint_as_float(((unsigned)v) << 16);
}

__device__ __forceinline__ void cvt_store8(unsigned short* lp, const float* gp) {
    float4 a = *(const float4*)gp;
    float4 b = *(const float4*)(gp + 4);
    s16x4 p0 = {(short)f2bf(a.x), (short)f2bf(a.y), (short)f2bf(a.z), (short)f2bf(a.w)};
    s16x4 p1 = {(short)f2bf(b.x), (short)f2bf(b.y), (short)f2bf(b.z), (short)f2bf(b.w)};
    *(s16x4*)lp = p0;
    *(s16x4*)(lp + 4) = p1;
}

// ---------------- one-time prep: dist -> bf16 padded [32][1000][1024] ----------------
__global__ __launch_bounds__(256) void k_prep(
        const float* __restrict__ dist, unsigned short* __restrict__ nd) {
    int row = blockIdx.x;             // b*1000 + i
    int col = threadIdx.x * 4;
    unsigned short* op = nd + (size_t)row * 1024 + col;
    if (col < 1000) {
        float4 v = *(const float4*)(dist + (size_t)row * 1000 + col);
        s16x4 p = {(short)f2bf(v.x), (short)f2bf(v.y), (short)f2bf(v.z), (short)f2bf(v.w)};
        *(s16x4*)op = p;
    } else {
        s16x4 z = {0, 0, 0, 0};
        *(s16x4*)op = z;
    }
}

// ---------------- embedding ----------------
__global__ __launch_bounds__(128) void k_embed(
        const float* __restrict__ depot, const float* __restrict__ node,
        const float* __restrict__ Wd, const float* __restrict__ bd,
        const float* __restrict__ Wn, const float* __restrict__ bn,
        float* __restrict__ x) {
    int row = blockIdx.x;
    int b = row / S, s = row % S;
    int d = threadIdx.x;
    float o;
    if (s == 0) {
        float x0 = depot[b * 2 + 0], x1 = depot[b * 2 + 1];
        o = Wd[d * 2 + 0] * x0 + Wd[d * 2 + 1] * x1 + bd[d];
    } else {
        const float* p = node + ((size_t)b * NN + (s - 1)) * 3;
        o = Wn[d * 3 + 0] * p[0] + Wn[d * 3 + 1] * p[1] + Wn[d * 3 + 2] * p[2] + bn[d];
    }
    x[(size_t)row * D + d] = o;
}

__global__ __launch_bounds__(128) void k_rowxform(
        float* __restrict__ x, const float* __restrict__ W,
        const float* __restrict__ bias, const int* __restrict__ flag, int mode) {
    int b = blockIdx.x;
    int d = threadIdx.x;
    __shared__ float row[D];
    int r = (mode == 0) ? 1 : (1 - flag[b]) * NN;
    float* xr = x + ((size_t)b * S + r) * D;
    row[d] = xr[d];
    __syncthreads();
    float acc = bias[d];
    for (int e = 0; e < D; e += 4) {
        const float4 w = *(const float4*)(W + (size_t)d * D + e);
        acc += w.x * row[e] + w.y * row[e + 1] + w.z * row[e + 2] + w.w * row[e + 3];
    }
    xr[d] = acc;
}

// ---------------- qkv GEMM (MFMA) -> sq fp32, mT chunk-major swizzled bf16 ----------------
// mT layout: [b][kc=16][d=256][8 slots of 8 shorts]; slot s' holds k-octet (s' ^ (d&7))
__global__ __launch_bounds__(256) void k_qkv(
        const float* __restrict__ x,
        const float* __restrict__ Wq, const float* __restrict__ Wk, const float* __restrict__ Wv,
        float* __restrict__ sq, unsigned short* __restrict__ mT) {
    int blk = blockIdx.x;
    int b = blk >> 4, rb = blk & 15;
    int s0 = rb * 64;
    int tid = threadIdx.x, lane = tid & 63, wid = tid >> 6;
    __shared__ unsigned short lds[17920];     // xs[64*40] + wt[3][128*40]
    unsigned short* xs = lds;
    unsigned short* wt0 = lds + 2560;
    f32x4 acc[3][8];
#pragma unroll
    for (int mm = 0; mm < 3; mm++)
#pragma unroll
        for (int cf = 0; cf < 8; cf++) acc[mm][cf] = {0.f, 0.f, 0.f, 0.f};

    for (int k0 = 0; k0 < D; k0 += 32) {
        {
            int i = tid >> 2, kq = (tid & 3) * 8;
            int s = s0 + i;
            int gs = s < S ? s : S - 1;
            cvt_store8(&xs[i * 40 + kq], x + ((size_t)b * S + gs) * D + k0 + kq);
        }
#pragma unroll
        for (int u0 = 0; u0 < 6; u0++) {
            int u = tid + u0 * 256;
            int mm = u >> 9;
            int v = u & 511;
            int c = v >> 2, kq = (v & 3) * 8;
            const float* Wsrc = (mm == 0) ? Wq : (mm == 1) ? Wk : Wv;
            cvt_store8(&wt0[mm * 5120 + c * 40 + kq], Wsrc + (size_t)c * D + k0 + kq);
        }
        __syncthreads();
#pragma unroll
        for (int ks = 0; ks < 2; ks++) {
            int ko = ks * 16 + (lane >> 4) * 4;
            s16x4 a = *(const s16x4*)&xs[(wid * 16 + (lane & 15)) * 40 + ko];
#pragma unroll
            for (int mm = 0; mm < 3; mm++)
#pragma unroll
                for (int cf = 0; cf < 8; cf++) {
                    s16x4 bf = *(const s16x4*)&wt0[mm * 5120 + (cf * 16 + (lane & 15)) * 40 + ko];
                    acc[mm][cf] = MFMA16(a, bf, acc[mm][cf]);
                }
        }
        __syncthreads();
    }

    // epilogue: build m tile [64 s][264 pad] in LDS, transpose out to mT
    unsigned short* tile = lds;               // 64*264 = 16896 <= 17920
    if (rb == 15) {
        for (int idx = tid; idx < 24 * 264; idx += 256) tile[40 * 264 + idx] = 0;
    }
#pragma unroll
    for (int cf = 0; cf < 8; cf++) {
        int d = cf * 16 + (lane & 15);
#pragma unroll
        for (int r = 0; r < 4; r++) {
            int sl = wid * 16 + (lane >> 4) * 4 + r;
            int s = s0 + sl;
            if (s < S) {
                float qv = acc[0][cf][r], kv = acc[1][cf][r], vv = acc[2][cf][r];
                float ek = __expf(kv);
                sq[((size_t)b * S + s) * D + d] = 1.f / (1.f + __expf(-qv));
                tile[sl * 264 + d] = f2bf(ek * vv);
                tile[sl * 264 + 128 + d] = f2bf(ek);
            }
        }
    }
    __syncthreads();
    {
        int ko8 = tid & 7;                    // k-octet index
        int d0 = (tid >> 3) * 8;
        s16x8 q[8];
#pragma unroll
        for (int jj = 0; jj < 8; jj++)
            q[jj] = *(const s16x8*)&tile[(ko8 * 8 + jj) * 264 + d0];
        unsigned short* base = mT + (((size_t)b * 16 + rb) * 256) * 64;
#pragma unroll
        for (int j = 0; j < 8; j++) {
            s16x8 o = {q[0][j], q[1][j], q[2][j], q[3][j],
                       q[4][j], q[5][j], q[6][j], q[7][j]};
            int d = d0 + j;
            int slot = ko8 ^ (d & 7);
            *(s16x8*)(base + (size_t)d * 64 + slot * 8) = o;
        }
    }
}

// ---------------- attention (MFMA 16x16x32, swizzled LDS, 4 blocks/CU) ----------------
__global__ __launch_bounds__(256, 4) void k_attn(
        const float* __restrict__ x, const float* __restrict__ sqb,
        const unsigned short* __restrict__ mT, const unsigned short* __restrict__ nd,
        const float* __restrict__ log_scale, const float* __restrict__ alpha, int l,
        float* __restrict__ y) {
    int blk = blockIdx.x;
    int b = blk >> 4, ib = blk & 15;
    int i0 = ib * 64;
    int tid = threadIdx.x, lane = tid & 63, wid = tid >> 6;
    __shared__ unsigned short esL[64 * 64];   // 8 KB, swizzled rows of 128B
    __shared__ unsigned short mtL[256 * 64];  // 32 KB, linear copy of swizzled mT chunk
    float sc = log_scale[0] * alpha[l];
    f32x4 acc[16];
#pragma unroll
    for (int cf = 0; cf < 16; cf++) acc[cf] = {0.f, 0.f, 0.f, 0.f};
    const unsigned short* ndb = nd + (size_t)b * 1000 * 1024;
    const unsigned short* mtb = mT + (size_t)b * 16 * 256 * 64;

    int erow = tid >> 2;
    int gi = i0 + erow; if (gi > 999) gi = 999;
    const unsigned short* ndr = ndb + (size_t)gi * 1024 + (tid & 3) * 16;
    int eg = (tid & 3) * 2;
    unsigned short* esw0 = &esL[erow * 64 + ((eg) ^ (erow & 7)) * 8];
    unsigned short* esw1 = &esL[erow * 64 + ((eg + 1) ^ (erow & 7)) * 8];

    for (int kc = 0; kc < 16; kc++) {
        __syncthreads();
        // stage es chunk: exp(-sc * nd)
        {
            s16x8 r0 = *(const s16x8*)(ndr + kc * 64);
            s16x8 r1 = *(const s16x8*)(ndr + kc * 64 + 8);
            s16x8 o0, o1;
#pragma unroll
            for (int j = 0; j < 8; j++) {
                o0[j] = (short)f2bf(__expf(-sc * bf2f((unsigned short)r0[j])));
                o1[j] = (short)f2bf(__expf(-sc * bf2f((unsigned short)r1[j])));
            }
            *(s16x8*)esw0 = o0;
            *(s16x8*)esw1 = o1;
        }
        // stage mT chunk (pure 32KB copy, coalesced, conflict-free)
#pragma unroll
        for (int i = 0; i < 8; i++) {
            int idx = i * 256 + tid;
            s16x8 v = *(const s16x8*)(mtb + (size_t)kc * 16384 + (size_t)idx * 8);
            *(s16x8*)(&mtL[idx * 8]) = v;
        }
        __syncthreads();
#pragma unroll
        for (int ks = 0; ks < 2; ks++) {
            int arow = wid * 16 + (lane & 15);
            int ag = ks * 4 + (lane >> 4);
            s16x8 a = *(const s16x8*)&esL[arow * 64 + ((ag ^ (arow & 7)) * 8)];
            __builtin_amdgcn_s_setprio(1);
#pragma unroll
            for (int cf = 0; cf < 16; cf++) {
                int c = (cf & 7) * 16 + (cf >> 3) * 128 + (lane & 15);
                s16x8 bf = *(const s16x8*)&mtL[c * 64 + ((ag ^ (c & 7)) * 8)];
                acc[cf] = MFMA32(a, bf, acc[cf]);
            }
            __builtin_amdgcn_s_setprio(0);
        }
    }
#pragma unroll
    for (int cf = 0; cf < 8; cf++) {
        int d = cf * 16 + (lane & 15);
#pragma unroll
        for (int r = 0; r < 4; r++) {
            int i = i0 + wid * 16 + (lane >> 4) * 4 + r;
            if (i < S) {
                size_t off = ((size_t)b * S + i) * D + d;
                float w = n2n(acc[cf][r]) / n2n(acc[cf + 8][r]);
                y[off] = x[off] + sqb[off] * w;
            }
        }
    }
}

// ---------------- instance-norm ----------------
__global__ __launch_bounds__(128) void k_nstat(
        const float* __restrict__ y, float* __restrict__ part) {
    int b = blockIdx.x >> 3;
    int c = blockIdx.x & 7;
    int d = threadIdx.x;
    const float* p = y + ((size_t)b * S + c * 125) * D + d;
    float s = 0.f, s2 = 0.f;
    for (int r = 0; r < 125; r++) {
        float v = p[(size_t)r * D];
        s += v;
        s2 = fmaf(v, v, s2);
    }
    part[(size_t)blockIdx.x * 2 * D + d] = s;
    part[(size_t)blockIdx.x * 2 * D + D + d] = s2;
}

__global__ __launch_bounds__(256) void k_finalize(
        const float* __restrict__ part, float* __restrict__ acc) {
    int i = blockIdx.x * 256 + threadIdx.x;
    int b = i / (2 * D), k = i - b * 2 * D;
    float s = 0.f;
    for (int c = 0; c < 8; c++) s += part[(size_t)(b * 8 + c) * 2 * D + k];
    acc[i] = s;
}

__global__ __launch_bounds__(256) void k_norm(
        const float* __restrict__ y, const float* __restrict__ acc,
        const float* __restrict__ g, const float* __restrict__ bb,
        float* __restrict__ out) {
    size_t i = (size_t)blockIdx.x * 256 + threadIdx.x;
    int d = (int)(i % D);
    int b = (int)(i / ((size_t)S * D));
    float mu = acc[b * 2 * D + d] * (1.f / S);
    float var = acc[b * 2 * D + D + d] * (1.f / S) - mu * mu;
    float v = (y[i] - mu) * rsqrtf(var + EPSN);
    out[i] = v * g[d] + bb[d];
}

// ---------------- FFN (MFMA) ----------------
__global__ __launch_bounds__(256) void k_ff1(
        const float* __restrict__ h, const float* __restrict__ W1,
        const float* __restrict__ bW1, unsigned short* __restrict__ t) {
    int blk = blockIdx.x;
    int rb = blk >> 1, cb = blk & 1;
    int r0 = rb * 64, c0 = cb * 256;
    int tid = threadIdx.x, lane = tid & 63, wid = tid >> 6;
    __shared__ unsigned short hs[64 * 40];
    __shared__ unsigned short ws[256 * 40];
    f32x4 acc[16];
#pragma unroll
    for (int cf = 0; cf < 16; cf++) acc[cf] = {0.f, 0.f, 0.f, 0.f};

    for (int k0 = 0; k0 < D; k0 += 32) {
        {
            int i = tid >> 2, kq = (tid & 3) * 8;
            cvt_store8(&hs[i * 40 + kq], h + (size_t)(r0 + i) * D + k0 + kq);
        }
#pragma unroll
        for (int kq8 = 0; kq8 < 4; kq8++)
            cvt_store8(&ws[tid * 40 + kq8 * 8], W1 + (size_t)(c0 + tid) * D + k0 + kq8 * 8);
        __syncthreads();
#pragma unroll
        for (int ks = 0; ks < 2; ks++) {
            int ko = ks * 16 + (lane >> 4) * 4;
            s16x4 a = *(const s16x4*)&hs[(wid * 16 + (lane & 15)) * 40 + ko];
#pragma unroll
            for (int cf = 0; cf < 16; cf++) {
                s16x4 bf = *(const s16x4*)&ws[(cf * 16 + (lane & 15)) * 40 + ko];
                acc[cf] = MFMA16(a, bf, acc[cf]);
            }
        }
        __syncthreads();
    }
#pragma unroll
    for (int cf = 0; cf < 16; cf++) {
        int c = c0 + cf * 16 + (lane & 15);
        float bias = bW1[c];
#pragma unroll
        for (int r = 0; r < 4; r++) {
            int row = r0 + wid * 16 + (lane >> 4) * 4 + r;
            float v = acc[cf][r] + bias;
            t[(size_t)row * F + c] = f2bf(fmaxf(v, 0.f));
        }
    }
}

__global__ __launch_bounds__(256) void k_ff2(
        const unsigned short* __restrict__ t, const float* __restrict__ h,
        const float* __restrict__ W2, const float* __restrict__ bW2,
        float* __restrict__ y) {
    int blk = blockIdx.x;
    int r0 = blk * 64;
    int tid = threadIdx.x, lane = tid & 63, wid = tid >> 6;
    __shared__ unsigned short ts[64 * 40];
    __shared__ unsigned short ws[128 * 40];
    f32x4 acc[8];
#pragma unroll
    for (int cf = 0; cf < 8; cf++) acc[cf] = {0.f, 0.f, 0.f, 0.f};

    for (int k0 = 0; k0 < F; k0 += 32) {
        {
            int i = tid >> 2, kq = (tid & 3) * 8;
            const unsigned short* tp = t + (size_t)(r0 + i) * F + k0 + kq;
            s16x4 v0 = *(const s16x4*)tp;
            s16x4 v1 = *(const s16x4*)(tp + 4);
            *(s16x4*)&ts[i * 40 + kq] = v0;
            *(s16x4*)&ts[i * 40 + kq + 4] = v1;
        }
        {
            int c = tid >> 1, kq = (tid & 1) * 16;
            cvt_store8(&ws[c * 40 + kq], W2 + (size_t)c * F + k0 + kq);
            cvt_store8(&ws[c * 40 + kq + 8], W2 + (size_t)c * F + k0 + kq + 8);
        }
        __syncthreads();
#pragma unroll
        for (int ks = 0; ks < 2; ks++) {
            int ko = ks * 16 + (lane >> 4) * 4;
            s16x4 a = *(const s16x4*)&ts[(wid * 16 + (lane & 15)) * 40 + ko];
#pragma unroll
            for (int cf = 0; cf < 8; cf++) {
                s16x4 bf = *(const s16x4*)&ws[(cf * 16 + (lane & 15)) * 40 + ko];
                acc[cf] = MFMA16(a, bf, acc[cf]);
            }
        }
        __syncthreads();
    }
#pragma unroll
    for (int cf = 0; cf < 8; cf++) {
        int c = cf * 16 + (lane & 15);
        float bias = bW2[c];
#pragma unroll
        for (int r = 0; r < 4; r++) {
            int row = r0 + wid * 16 + (lane >> 4) * 4 + r;
            size_t off = (size_t)row * D + c;
            y[off] = h[off] + acc[cf][r] + bias;
        }
    }
}

extern "C" void kernel_launch(void* const* d_in, const int* in_sizes, int n_in,
                              void* d_out, int out_size, void* d_ws, size_t ws_size,
                              hipStream_t stream) {
    const float* depot = (const float*)d_in[0];
    const float* node  = (const float*)d_in[1];
    const float* dist  = (const float*)d_in[2];
    const float* log_scale = (const float*)d_in[3];
    const int*   flag  = (const int*)d_in[4];
    const float* Wd   = (const float*)d_in[5];
    const float* bd   = (const float*)d_in[6];
    const float* Wn   = (const float*)d_in[7];
    const float* bn   = (const float*)d_in[8];
    const float* Win  = (const float*)d_in[9];
    const float* bin_ = (const float*)d_in[10];
    const float* Wout = (const float*)d_in[11];
    const float* bout = (const float*)d_in[12];
    const float* Wq   = (const float*)d_in[13];
    const float* Wk   = (const float*)d_in[14];
    const float* Wv   = (const float*)d_in[15];
    const float* alpha= (const float*)d_in[16];
    const float* g1   = (const float*)d_in[17];
    const float* b1   = (const float*)d_in[18];
    const float* W1   = (const float*)d_in[19];
    const float* bW1  = (const float*)d_in[20];
    const float* W2   = (const float*)d_in[21];
    const float* bW2  = (const float*)d_in[22];
    const float* g2   = (const float*)d_in[23];
    const float* b2   = (const float*)d_in[24];

    float* ws = (float*)d_ws;
    size_t nxd = (size_t)B * S * D;                       // 4,096,000
    float* x    = ws;
    float* sqb  = ws + nxd;
    float* y    = ws + 2 * nxd;
    float* h    = ws + 3 * nxd;
    float* part = ws + 4 * nxd;                           // B*8*2*D = 65536
    float* accb = part + (size_t)B * 8 * 2 * D;           // B*2*D = 8192
    unsigned short* mT = (unsigned short*)(accb + (size_t)B * 2 * D);   // B*16*256*64
    unsigned short* t  = mT + (size_t)B * 16 * 256 * 64;                // B*S*F
    unsigned short* nd = t + (size_t)B * S * F;                         // B*1000*1024

    k_prep<<<B * S, 256, 0, stream>>>(dist, nd);
    k_embed<<<B * S, 128, 0, stream>>>(depot, node, Wd, bd, Wn, bn, x);
    k_rowxform<<<B, 128, 0, stream>>>(x, Win, bin_, flag, 0);
    k_rowxform<<<B, 128, 0, stream>>>(x, Wout, bout, flag, 1);

    for (int l = 0; l < L; l++) {
        k_qkv<<<B * 16, 256, 0, stream>>>(x, Wq + (size_t)l * D * D,
                                          Wk + (size_t)l * D * D,
                                          Wv + (size_t)l * D * D, sqb, mT);
        k_attn<<<B * 16, 256, 0, stream>>>(x, sqb, mT, nd, log_scale, alpha, l, y);
        k_nstat<<<B * 8, 128, 0, stream>>>(y, part);
        k_finalize<<<32, 256, 0, stream>>>(part, accb);
        k_norm<<<B * S * D / 256, 256, 0, stream>>>(y, accb, g1 + l * D, b1 + l * D, h);
        k_ff1<<<(B * S / 64) * 2, 256, 0, stream>>>(h, W1 + (size_t)l * F * D, bW1 + (size_t)l * F, t);
        k_ff2<<<B * S / 64, 256, 0, stream>>>(t, h, W2 + (size_t)l * D * F, bW2 + (size_t)l * D, y);
        k_nstat<<<B * 8, 128, 0, stream>>>(y, part);
        k_finalize<<<32, 256, 0, stream>>>(part, accb);
        float* dst = (l == L - 1) ? (float*)d_out : x;
        k_norm<<<B * S * D / 256, 256, 0, stream>>>(y, accb, g2 + l * D, b2 + l * D, dst);
    }
}

// Round 4
// 958.270 us; speedup vs baseline: 1.2168x; 1.2168x over previous
//
#include <hip/hip_runtime.h>
#include <hip/hip_bf16.h>
#include <float.h>
#include <math.h>

#define B 32
#define NN 999
#define S 1000
#define D 128
#define F 512
#define L 6
#define EPSN 1e-5f

typedef __attribute__((ext_vector_type(4))) float f32x4;
typedef __attribute__((ext_vector_type(4))) short s16x4;
typedef __attribute__((ext_vector_type(8))) short s16x8;

#if defined(__has_builtin)
#if __has_builtin(__builtin_amdgcn_mfma_f32_16x16x16bf16_1k)
#define HAVE_MFMA16 1
#endif
#if __has_builtin(__builtin_amdgcn_mfma_f32_16x16x32_bf16)
#define HAVE_MFMA32 1
#endif
#endif

#ifdef HAVE_MFMA16
#define MFMA16(a, b, c) __builtin_amdgcn_mfma_f32_16x16x16bf16_1k((a), (b), (c), 0, 0, 0)
#else
static __device__ __forceinline__ f32x4 mfma16_asm(s16x4 a, s16x4 b, f32x4 c) {
    asm volatile("v_mfma_f32_16x16x16_bf16 %0, %1, %2, %0\n\ts_nop 7\n\ts_nop 7"
                 : "+v"(c) : "v"(a), "v"(b));
    return c;
}
#define MFMA16(a, b, c) mfma16_asm((a), (b), (c))
#endif

#ifdef HAVE_MFMA32
#define MFMA32(a, b, c) __builtin_amdgcn_mfma_f32_16x16x32_bf16((a), (b), (c), 0, 0, 0)
#else
static __device__ __forceinline__ f32x4 mfma32_asm(s16x8 a, s16x8 b, f32x4 c) {
    asm volatile("v_mfma_f32_16x16x32_bf16 %0, %1, %2, %0\n\ts_nop 7\n\ts_nop 7"
                 : "+v"(c) : "v"(a), "v"(b));
    return c;
}
#define MFMA32(a, b, c) mfma32_asm((a), (b), (c))
#endif

__device__ __forceinline__ float n2n(float v) {
    if (v != v) return 0.f;
    if (isinf(v)) return v > 0.f ? FLT_MAX : -FLT_MAX;
    return v;
}

__device__ __forceinline__ unsigned short f2bf(float x) {
    unsigned u = __float_as_uint(x);
    return (unsigned short)((u + 0x7fffu + ((u >> 16) & 1u)) >> 16);
}

__device__ __forceinline__ float bf2f(unsigned short v) {
    return __uint_as_float(((unsigned)v) << 16);
}

// ---------------- one-time prep ----------------
__global__ __launch_bounds__(256) void k_prep(
        const float* __restrict__ dist, unsigned short* __restrict__ nd) {
    int row = blockIdx.x;             // b*1000 + i
    int col = threadIdx.x * 4;
    unsigned short* op = nd + (size_t)row * 1024 + col;
    if (col < 1000) {
        float4 v = *(const float4*)(dist + (size_t)row * 1000 + col);
        s16x4 p = {(short)f2bf(v.x), (short)f2bf(v.y), (short)f2bf(v.z), (short)f2bf(v.w)};
        *(s16x4*)op = p;
    } else {
        s16x4 z = {0, 0, 0, 0};
        *(s16x4*)op = z;
    }
}

__global__ __launch_bounds__(128) void k_embed(
        const float* __restrict__ depot, const float* __restrict__ node,
        const float* __restrict__ Wd, const float* __restrict__ bd,
        const float* __restrict__ Wn, const float* __restrict__ bn,
        float* __restrict__ x) {
    int row = blockIdx.x;
    int b = row / S, s = row % S;
    int d = threadIdx.x;
    float o;
    if (s == 0) {
        float x0 = depot[b * 2 + 0], x1 = depot[b * 2 + 1];
        o = Wd[d * 2 + 0] * x0 + Wd[d * 2 + 1] * x1 + bd[d];
    } else {
        const float* p = node + ((size_t)b * NN + (s - 1)) * 3;
        o = Wn[d * 3 + 0] * p[0] + Wn[d * 3 + 1] * p[1] + Wn[d * 3 + 2] * p[2] + bn[d];
    }
    x[(size_t)row * D + d] = o;
}

__global__ __launch_bounds__(128) void k_rowxform(
        float* __restrict__ x, const float* __restrict__ W,
        const float* __restrict__ bias, const int* __restrict__ flag, int mode) {
    int b = blockIdx.x;
    int d = threadIdx.x;
    __shared__ float row[D];
    int r = (mode == 0) ? 1 : (1 - flag[b]) * NN;
    float* xr = x + ((size_t)b * S + r) * D;
    row[d] = xr[d];
    __syncthreads();
    float acc = bias[d];
    for (int e = 0; e < D; e += 4) {
        const float4 w = *(const float4*)(W + (size_t)d * D + e);
        acc += w.x * row[e] + w.y * row[e + 1] + w.z * row[e + 2] + w.w * row[e + 3];
    }
    xr[d] = acc;
}

// ---------------- qkv: reads y_prev (+norm fused), writes sq bf16, mT swizzled ----------------
__global__ __launch_bounds__(256) void k_qkv(
        const float* __restrict__ yprev, const float* __restrict__ accp,
        const float* __restrict__ gp, const float* __restrict__ bp, int hasnorm,
        const float* __restrict__ Wq, const float* __restrict__ Wk, const float* __restrict__ Wv,
        unsigned short* __restrict__ sqb, unsigned short* __restrict__ mT) {
    int blk = blockIdx.x;
    int b = blk >> 4, rb = blk & 15;
    int s0 = rb * 64;
    int tid = threadIdx.x, lane = tid & 63, wid = tid >> 6;
    __shared__ unsigned short lds[17920];     // xs[64*40] + wt[3][128*40]
    __shared__ float nsc[128], nsh[128];
    unsigned short* xs = lds;
    unsigned short* wt0 = lds + 2560;

    if (tid < 128) {
        float scv = 1.f, shv = 0.f;
        if (hasnorm) {
            float s1v = accp[b * 256 + tid], s2v = accp[b * 256 + 128 + tid];
            float mu = s1v * (1.f / S);
            float var = s2v * (1.f / S) - mu * mu;
            float rs = rsqrtf(var + EPSN);
            scv = rs * gp[tid];
            shv = bp[tid] - mu * scv;
        }
        nsc[tid] = scv; nsh[tid] = shv;
    }
    __syncthreads();

    f32x4 acc[3][8];
#pragma unroll
    for (int mm = 0; mm < 3; mm++)
#pragma unroll
        for (int cf = 0; cf < 8; cf++) acc[mm][cf] = {0.f, 0.f, 0.f, 0.f};

    for (int k0 = 0; k0 < D; k0 += 32) {
        {
            int i = tid >> 2, kq = (tid & 3) * 8;
            int s = s0 + i;
            int gs = s < S ? s : S - 1;
            const float* gpx = yprev + ((size_t)b * S + gs) * D + k0 + kq;
            float4 a4 = *(const float4*)gpx;
            float4 b4 = *(const float4*)(gpx + 4);
            const float* scp = &nsc[k0 + kq];
            const float* shp = &nsh[k0 + kq];
            s16x4 p0 = {(short)f2bf(a4.x * scp[0] + shp[0]), (short)f2bf(a4.y * scp[1] + shp[1]),
                        (short)f2bf(a4.z * scp[2] + shp[2]), (short)f2bf(a4.w * scp[3] + shp[3])};
            s16x4 p1 = {(short)f2bf(b4.x * scp[4] + shp[4]), (short)f2bf(b4.y * scp[5] + shp[5]),
                        (short)f2bf(b4.z * scp[6] + shp[6]), (short)f2bf(b4.w * scp[7] + shp[7])};
            *(s16x4*)&xs[i * 40 + kq] = p0;
            *(s16x4*)&xs[i * 40 + kq + 4] = p1;
        }
#pragma unroll
        for (int u0 = 0; u0 < 6; u0++) {
            int u = tid + u0 * 256;
            int mm = u >> 9;
            int v = u & 511;
            int c = v >> 2, kq = (v & 3) * 8;
            const float* Wsrc = (mm == 0) ? Wq : (mm == 1) ? Wk : Wv;
            const float* gw = Wsrc + (size_t)c * D + k0 + kq;
            float4 a4 = *(const float4*)gw;
            float4 b4 = *(const float4*)(gw + 4);
            s16x4 p0 = {(short)f2bf(a4.x), (short)f2bf(a4.y), (short)f2bf(a4.z), (short)f2bf(a4.w)};
            s16x4 p1 = {(short)f2bf(b4.x), (short)f2bf(b4.y), (short)f2bf(b4.z), (short)f2bf(b4.w)};
            *(s16x4*)&wt0[mm * 5120 + c * 40 + kq] = p0;
            *(s16x4*)&wt0[mm * 5120 + c * 40 + kq + 4] = p1;
        }
        __syncthreads();
#pragma unroll
        for (int ks = 0; ks < 2; ks++) {
            int ko = ks * 16 + (lane >> 4) * 4;
            s16x4 a = *(const s16x4*)&xs[(wid * 16 + (lane & 15)) * 40 + ko];
#pragma unroll
            for (int mm = 0; mm < 3; mm++)
#pragma unroll
                for (int cf = 0; cf < 8; cf++) {
                    s16x4 bf = *(const s16x4*)&wt0[mm * 5120 + (cf * 16 + (lane & 15)) * 40 + ko];
                    acc[mm][cf] = MFMA16(a, bf, acc[mm][cf]);
                }
        }
        __syncthreads();
    }

    // epilogue: direct swizzled global stores of mT (chunk index == rb)
    int sl0 = wid * 16 + (lane >> 4) * 4;     // local k of first r
    int oct = sl0 >> 3, wo = sl0 & 7;
    unsigned short* base = mT + (((size_t)b * 16 + rb) * 256) * 64;
#pragma unroll
    for (int cf = 0; cf < 8; cf++) {
        int d = cf * 16 + (lane & 15);
        s16x4 p0, p1;
#pragma unroll
        for (int r = 0; r < 4; r++) {
            int s = s0 + sl0 + r;
            if (s < S) {
                float qv = acc[0][cf][r], kv = acc[1][cf][r], vv = acc[2][cf][r];
                float ek = __expf(kv);
                sqb[((size_t)b * S + s) * D + d] = f2bf(1.f / (1.f + __expf(-qv)));
                p0[r] = (short)f2bf(ek * vv);
                p1[r] = (short)f2bf(ek);
            } else { p0[r] = 0; p1[r] = 0; }
        }
        int slot = oct ^ (d & 7);
        *(s16x4*)(base + (size_t)d * 64 + slot * 8 + wo) = p0;
        *(s16x4*)(base + (size_t)(d + 128) * 64 + slot * 8 + wo) = p1;
    }
}

// ---------------- attention: pipelined reg-staging, fused residual-norm + stats ----------------
__global__ __launch_bounds__(256) void k_attn(
        const float* __restrict__ yprev, const float* __restrict__ accp,
        const float* __restrict__ gp, const float* __restrict__ bp, int hasnorm,
        const unsigned short* __restrict__ sqb,
        const unsigned short* __restrict__ mT, const unsigned short* __restrict__ nd,
        const float* __restrict__ log_scale, const float* __restrict__ alpha, int l,
        float* __restrict__ y, float* __restrict__ part) {
    int blk0 = blockIdx.x;
    int blk = (blk0 & 7) * 64 + (blk0 >> 3);  // XCD-bijective swizzle (512 % 8 == 0)
    int b = blk >> 4, ib = blk & 15;
    int i0 = ib * 64;
    int tid = threadIdx.x, lane = tid & 63, wid = tid >> 6;
    __shared__ unsigned short esL[64 * 64];   // 8 KB swizzled
    __shared__ unsigned short mtL[256 * 64];  // 32 KB linear copy of swizzled mT chunk
    float sc = log_scale[0] * alpha[l];

    float rsc[8], rsh[8];
#pragma unroll
    for (int cf = 0; cf < 8; cf++) {
        int d = cf * 16 + (lane & 15);
        float scv = 1.f, shv = 0.f;
        if (hasnorm) {
            float s1v = accp[b * 256 + d], s2v = accp[b * 256 + 128 + d];
            float mu = s1v * (1.f / S);
            float var = s2v * (1.f / S) - mu * mu;
            float rs = rsqrtf(var + EPSN);
            scv = rs * gp[d];
            shv = bp[d] - mu * scv;
        }
        rsc[cf] = scv; rsh[cf] = shv;
    }

    f32x4 acc[16];
#pragma unroll
    for (int cf = 0; cf < 16; cf++) acc[cf] = {0.f, 0.f, 0.f, 0.f};

    int erow = tid >> 2;
    int gi = i0 + erow; if (gi > 999) gi = 999;
    const unsigned short* ndr = nd + (size_t)b * 1000 * 1024 + (size_t)gi * 1024 + (tid & 3) * 16;
    const unsigned short* mtb = mT + (size_t)b * 16 * 16384;
    int eg = (tid & 3) * 2;
    unsigned short* esw0 = &esL[erow * 64 + ((eg) ^ (erow & 7)) * 8];
    unsigned short* esw1 = &esL[erow * 64 + ((eg + 1) ^ (erow & 7)) * 8];

    // prologue: chunk 0 into regs
    s16x8 cnA = *(const s16x8*)(ndr);
    s16x8 cnB = *(const s16x8*)(ndr + 8);
    s16x8 cm[8];
#pragma unroll
    for (int i2 = 0; i2 < 8; i2++)
        cm[i2] = *(const s16x8*)(mtb + (size_t)(i2 * 256 + tid) * 8);

    for (int kc = 0; kc < 16; kc++) {
        // exp-pack current nd regs
        s16x8 o0, o1;
#pragma unroll
        for (int j = 0; j < 8; j++) {
            o0[j] = (short)f2bf(__expf(-sc * bf2f((unsigned short)cnA[j])));
            o1[j] = (short)f2bf(__expf(-sc * bf2f((unsigned short)cnB[j])));
        }
        int kn = kc < 15 ? kc + 1 : 15;
        // issue next-chunk nd loads (cold HBM stream -> longest lead time)
        cnA = *(const s16x8*)(ndr + kn * 64);
        cnB = *(const s16x8*)(ndr + kn * 64 + 8);
        __syncthreads();
        *(s16x8*)esw0 = o0;
        *(s16x8*)esw1 = o1;
#pragma unroll
        for (int i2 = 0; i2 < 8; i2++)
            *(s16x8*)&mtL[(i2 * 256 + tid) * 8] = cm[i2];
        // issue next-chunk mT loads; in flight across the MFMA phase
#pragma unroll
        for (int i2 = 0; i2 < 8; i2++)
            cm[i2] = *(const s16x8*)(mtb + (size_t)kn * 16384 + (size_t)(i2 * 256 + tid) * 8);
        __syncthreads();
#pragma unroll
        for (int ks = 0; ks < 2; ks++) {
            int arow = wid * 16 + (lane & 15);
            int ag = ks * 4 + (lane >> 4);
            s16x8 a = *(const s16x8*)&esL[arow * 64 + ((ag ^ (arow & 7)) * 8)];
            __builtin_amdgcn_s_setprio(1);
#pragma unroll
            for (int cf = 0; cf < 16; cf++) {
                int c = (cf & 7) * 16 + (cf >> 3) * 128 + (lane & 15);
                s16x8 bf = *(const s16x8*)&mtL[c * 64 + ((ag ^ (c & 7)) * 8)];
                acc[cf] = MFMA32(a, bf, acc[cf]);
            }
            __builtin_amdgcn_s_setprio(0);
        }
    }

    // epilogue: y = normed_residual + sq*w, plus instance-norm partial stats
    __syncthreads();
    float* pw = (float*)mtL;                  // reuse 4 KB
#pragma unroll
    for (int cf = 0; cf < 8; cf++) {
        int d = cf * 16 + (lane & 15);
        float s = 0.f, s2 = 0.f;
#pragma unroll
        for (int r = 0; r < 4; r++) {
            int i = i0 + wid * 16 + (lane >> 4) * 4 + r;
            if (i < S) {
                size_t off = ((size_t)b * S + i) * D + d;
                float w = n2n(acc[cf][r]) / n2n(acc[cf + 8][r]);
                float xv = yprev[off] * rsc[cf] + rsh[cf];
                float yv = xv + bf2f(sqb[off]) * w;
                y[off] = yv;
                s += yv;
                s2 = fmaf(yv, yv, s2);
            }
        }
        s += __shfl_xor(s, 16); s += __shfl_xor(s, 32);
        s2 += __shfl_xor(s2, 16); s2 += __shfl_xor(s2, 32);
        if (lane < 16) {
            pw[(wid * 2 + 0) * 128 + d] = s;
            pw[(wid * 2 + 1) * 128 + d] = s2;
        }
    }
    __syncthreads();
    {
        int st = tid >> 7, d = tid & 127;
        float v = pw[(0 * 2 + st) * 128 + d] + pw[(1 * 2 + st) * 128 + d] +
                  pw[(2 * 2 + st) * 128 + d] + pw[(3 * 2 + st) * 128 + d];
        part[((size_t)(b * 16 + ib) * 2 + st) * 128 + d] = v;
    }
}

// ---------------- finalize: sum 16 chunk partials ----------------
__global__ __launch_bounds__(256) void k_finalize(
        const float* __restrict__ part, float* __restrict__ acc) {
    int i = blockIdx.x * 256 + threadIdx.x;   // B*256
    int b = i >> 8, k = i & 255;
    float s = 0.f;
#pragma unroll
    for (int c = 0; c < 16; c++) s += part[(size_t)(b * 16 + c) * 256 + k];
    acc[i] = s;
}

// ---------------- ff1: stages normed h from ya, writes relu bf16 t ----------------
__global__ __launch_bounds__(256) void k_ff1(
        const float* __restrict__ ya, const float* __restrict__ accp,
        const float* __restrict__ gp, const float* __restrict__ bp,
        const float* __restrict__ W1, const float* __restrict__ bW1,
        unsigned short* __restrict__ t) {
    int blk = blockIdx.x;
    int b = blk >> 5, sub = blk & 31;
    int rb = sub >> 1, cb = sub & 1;
    int r0 = rb * 64, c0 = cb * 256;
    int tid = threadIdx.x, lane = tid & 63, wid = tid >> 6;
    __shared__ unsigned short hs[64 * 40];
    __shared__ unsigned short ws[256 * 40];
    __shared__ float nsc[128], nsh[128];

    if (tid < 128) {
        float s1v = accp[b * 256 + tid], s2v = accp[b * 256 + 128 + tid];
        float mu = s1v * (1.f / S);
        float var = s2v * (1.f / S) - mu * mu;
        float rs = rsqrtf(var + EPSN);
        float scv = rs * gp[tid];
        nsc[tid] = scv;
        nsh[tid] = bp[tid] - mu * scv;
    }
    __syncthreads();

    f32x4 acc[16];
#pragma unroll
    for (int cf = 0; cf < 16; cf++) acc[cf] = {0.f, 0.f, 0.f, 0.f};

    for (int k0 = 0; k0 < D; k0 += 32) {
        {
            int i = tid >> 2, kq = (tid & 3) * 8;
            int s = r0 + i; int gs = s < S ? s : S - 1;
            const float* gpx = ya + ((size_t)b * S + gs) * D + k0 + kq;
            float4 a4 = *(const float4*)gpx;
            float4 b4 = *(const float4*)(gpx + 4);
            const float* scp = &nsc[k0 + kq];
            const float* shp = &nsh[k0 + kq];
            s16x4 p0 = {(short)f2bf(a4.x * scp[0] + shp[0]), (short)f2bf(a4.y * scp[1] + shp[1]),
                        (short)f2bf(a4.z * scp[2] + shp[2]), (short)f2bf(a4.w * scp[3] + shp[3])};
            s16x4 p1 = {(short)f2bf(b4.x * scp[4] + shp[4]), (short)f2bf(b4.y * scp[5] + shp[5]),
                        (short)f2bf(b4.z * scp[6] + shp[6]), (short)f2bf(b4.w * scp[7] + shp[7])};
            *(s16x4*)&hs[i * 40 + kq] = p0;
            *(s16x4*)&hs[i * 40 + kq + 4] = p1;
        }
#pragma unroll
        for (int kq8 = 0; kq8 < 4; kq8++) {
            const float* gw = W1 + (size_t)(c0 + tid) * D + k0 + kq8 * 8;
            float4 a4 = *(const float4*)gw;
            float4 b4 = *(const float4*)(gw + 4);
            s16x4 p0 = {(short)f2bf(a4.x), (short)f2bf(a4.y), (short)f2bf(a4.z), (short)f2bf(a4.w)};
            s16x4 p1 = {(short)f2bf(b4.x), (short)f2bf(b4.y), (short)f2bf(b4.z), (short)f2bf(b4.w)};
            *(s16x4*)&ws[tid * 40 + kq8 * 8] = p0;
            *(s16x4*)&ws[tid * 40 + kq8 * 8 + 4] = p1;
        }
        __syncthreads();
#pragma unroll
        for (int ks = 0; ks < 2; ks++) {
            int ko = ks * 16 + (lane >> 4) * 4;
            s16x4 a = *(const s16x4*)&hs[(wid * 16 + (lane & 15)) * 40 + ko];
#pragma unroll
            for (int cf = 0; cf < 16; cf++) {
                s16x4 bf = *(const s16x4*)&ws[(cf * 16 + (lane & 15)) * 40 + ko];
                acc[cf] = MFMA16(a, bf, acc[cf]);
            }
        }
        __syncthreads();
    }
#pragma unroll
    for (int cf = 0; cf < 16; cf++) {
        int c = c0 + cf * 16 + (lane & 15);
        float bias = bW1[c];
#pragma unroll
        for (int r = 0; r < 4; r++) {
            int row = r0 + wid * 16 + (lane >> 4) * 4 + r;
            if (row < S) {
                float v = acc[cf][r] + bias;
                t[((size_t)b * S + row) * F + c] = f2bf(fmaxf(v, 0.f));
            }
        }
    }
}

// ---------------- ff2: residual-normed h + GEMM, writes yb + stats partials ----------------
__global__ __launch_bounds__(256) void k_ff2(
        const unsigned short* __restrict__ t, const float* __restrict__ ya,
        const float* __restrict__ accp, const float* __restrict__ gp, const float* __restrict__ bp,
        const float* __restrict__ W2, const float* __restrict__ bW2,
        float* __restrict__ yb, float* __restrict__ part) {
    int blk = blockIdx.x;
    int b = blk >> 4, rb = blk & 15;
    int r0 = rb * 64;
    int tid = threadIdx.x, lane = tid & 63, wid = tid >> 6;
    __shared__ unsigned short ts[64 * 40];
    __shared__ unsigned short ws[128 * 40];

    float rsc1[8], rsh1[8];
#pragma unroll
    for (int cf = 0; cf < 8; cf++) {
        int d = cf * 16 + (lane & 15);
        float s1v = accp[b * 256 + d], s2v = accp[b * 256 + 128 + d];
        float mu = s1v * (1.f / S);
        float var = s2v * (1.f / S) - mu * mu;
        float rs = rsqrtf(var + EPSN);
        rsc1[cf] = rs * gp[d];
        rsh1[cf] = bp[d] - mu * rsc1[cf];
    }

    f32x4 acc[8];
#pragma unroll
    for (int cf = 0; cf < 8; cf++) acc[cf] = {0.f, 0.f, 0.f, 0.f};

    for (int k0 = 0; k0 < F; k0 += 32) {
        {
            int i = tid >> 2, kq = (tid & 3) * 8;
            int s = r0 + i; int gs = s < S ? s : S - 1;
            const unsigned short* tp = t + ((size_t)b * S + gs) * F + k0 + kq;
            s16x4 v0 = *(const s16x4*)tp;
            s16x4 v1 = *(const s16x4*)(tp + 4);
            *(s16x4*)&ts[i * 40 + kq] = v0;
            *(s16x4*)&ts[i * 40 + kq + 4] = v1;
        }
        {
            int c = tid >> 1, kq = (tid & 1) * 16;
            const float* gw = W2 + (size_t)c * F + k0 + kq;
            float4 a4 = *(const float4*)gw;
            float4 b4 = *(const float4*)(gw + 4);
            float4 c4 = *(const float4*)(gw + 8);
            float4 d4 = *(const float4*)(gw + 12);
            s16x4 p0 = {(short)f2bf(a4.x), (short)f2bf(a4.y), (short)f2bf(a4.z), (short)f2bf(a4.w)};
            s16x4 p1 = {(short)f2bf(b4.x), (short)f2bf(b4.y), (short)f2bf(b4.z), (short)f2bf(b4.w)};
            s16x4 p2 = {(short)f2bf(c4.x), (short)f2bf(c4.y), (short)f2bf(c4.z), (short)f2bf(c4.w)};
            s16x4 p3 = {(short)f2bf(d4.x), (short)f2bf(d4.y), (short)f2bf(d4.z), (short)f2bf(d4.w)};
            *(s16x4*)&ws[c * 40 + kq] = p0;
            *(s16x4*)&ws[c * 40 + kq + 4] = p1;
            *(s16x4*)&ws[c * 40 + kq + 8] = p2;
            *(s16x4*)&ws[c * 40 + kq + 12] = p3;
        }
        __syncthreads();
#pragma unroll
        for (int ks = 0; ks < 2; ks++) {
            int ko = ks * 16 + (lane >> 4) * 4;
            s16x4 a = *(const s16x4*)&ts[(wid * 16 + (lane & 15)) * 40 + ko];
#pragma unroll
            for (int cf = 0; cf < 8; cf++) {
                s16x4 bf = *(const s16x4*)&ws[(cf * 16 + (lane & 15)) * 40 + ko];
                acc[cf] = MFMA16(a, bf, acc[cf]);
            }
        }
        __syncthreads();
    }

    __syncthreads();
    float* pw = (float*)ts;                   // reuse 4 KB
#pragma unroll
    for (int cf = 0; cf < 8; cf++) {
        int c = cf * 16 + (lane & 15);
        float bias = bW2[c];
        float s = 0.f, s2 = 0.f;
#pragma unroll
        for (int r = 0; r < 4; r++) {
            int row = r0 + wid * 16 + (lane >> 4) * 4 + r;
            if (row < S) {
                size_t off = ((size_t)b * S + row) * D + c;
                float hval = ya[off] * rsc1[cf] + rsh1[cf];
                float yv = hval + acc[cf][r] + bias;
                yb[off] = yv;
                s += yv;
                s2 = fmaf(yv, yv, s2);
            }
        }
        s += __shfl_xor(s, 16); s += __shfl_xor(s, 32);
        s2 += __shfl_xor(s2, 16); s2 += __shfl_xor(s2, 32);
        if (lane < 16) {
            pw[(wid * 2 + 0) * 128 + c] = s;
            pw[(wid * 2 + 1) * 128 + c] = s2;
        }
    }
    __syncthreads();
    {
        int st = tid >> 7, d = tid & 127;
        float v = pw[(0 * 2 + st) * 128 + d] + pw[(1 * 2 + st) * 128 + d] +
                  pw[(2 * 2 + st) * 128 + d] + pw[(3 * 2 + st) * 128 + d];
        part[((size_t)(b * 16 + rb) * 2 + st) * 128 + d] = v;
    }
}

// ---------------- final norm (last layer only) ----------------
__global__ __launch_bounds__(256) void k_norm(
        const float* __restrict__ y, const float* __restrict__ acc,
        const float* __restrict__ g, const float* __restrict__ bb,
        float* __restrict__ out) {
    size_t i = (size_t)blockIdx.x * 256 + threadIdx.x;
    int d = (int)(i % D);
    int b = (int)(i / ((size_t)S * D));
    float mu = acc[b * 256 + d] * (1.f / S);
    float var = acc[b * 256 + 128 + d] * (1.f / S) - mu * mu;
    float v = (y[i] - mu) * rsqrtf(var + EPSN);
    out[i] = v * g[d] + bb[d];
}

extern "C" void kernel_launch(void* const* d_in, const int* in_sizes, int n_in,
                              void* d_out, int out_size, void* d_ws, size_t ws_size,
                              hipStream_t stream) {
    const float* depot = (const float*)d_in[0];
    const float* node  = (const float*)d_in[1];
    const float* dist  = (const float*)d_in[2];
    const float* log_scale = (const float*)d_in[3];
    const int*   flag  = (const int*)d_in[4];
    const float* Wd   = (const float*)d_in[5];
    const float* bd   = (const float*)d_in[6];
    const float* Wn   = (const float*)d_in[7];
    const float* bn   = (const float*)d_in[8];
    const float* Win  = (const float*)d_in[9];
    const float* bin_ = (const float*)d_in[10];
    const float* Wout = (const float*)d_in[11];
    const float* bout = (const float*)d_in[12];
    const float* Wq   = (const float*)d_in[13];
    const float* Wk   = (const float*)d_in[14];
    const float* Wv   = (const float*)d_in[15];
    const float* alpha= (const float*)d_in[16];
    const float* g1   = (const float*)d_in[17];
    const float* b1   = (const float*)d_in[18];
    const float* W1   = (const float*)d_in[19];
    const float* bW1  = (const float*)d_in[20];
    const float* W2   = (const float*)d_in[21];
    const float* bW2  = (const float*)d_in[22];
    const float* g2   = (const float*)d_in[23];
    const float* b2   = (const float*)d_in[24];

    float* ws = (float*)d_ws;
    size_t nxd = (size_t)B * S * D;                       // 4,096,000
    float* ya    = ws;
    float* yb    = ws + nxd;
    float* part1 = ws + 2 * nxd;                          // B*16*256 = 131072
    float* part2 = part1 + 131072;
    float* accb1 = part2 + 131072;                        // B*256 = 8192
    float* accb2 = accb1 + 8192;
    unsigned short* sqb = (unsigned short*)(accb2 + 8192);          // B*S*D
    unsigned short* mT  = sqb + nxd;                                // B*16*256*64
    unsigned short* t   = mT + (size_t)B * 16 * 256 * 64;           // B*S*F
    unsigned short* nd  = t + (size_t)B * S * F;                    // B*1000*1024

    k_prep<<<B * S, 256, 0, stream>>>(dist, nd);
    k_embed<<<B * S, 128, 0, stream>>>(depot, node, Wd, bd, Wn, bn, yb);
    k_rowxform<<<B, 128, 0, stream>>>(yb, Win, bin_, flag, 0);
    k_rowxform<<<B, 128, 0, stream>>>(yb, Wout, bout, flag, 1);

    for (int l = 0; l < L; l++) {
        int hasnorm = (l > 0) ? 1 : 0;
        const float* gpn = g2 + (l > 0 ? (l - 1) : 0) * D;
        const float* bpn = b2 + (l > 0 ? (l - 1) : 0) * D;
        k_qkv<<<B * 16, 256, 0, stream>>>(yb, accb2, gpn, bpn, hasnorm,
                                          Wq + (size_t)l * D * D,
                                          Wk + (size_t)l * D * D,
                                          Wv + (size_t)l * D * D, sqb, mT);
        k_attn<<<B * 16, 256, 0, stream>>>(yb, accb2, gpn, bpn, hasnorm,
                                           sqb, mT, nd, log_scale, alpha, l, ya, part1);
        k_finalize<<<32, 256, 0, stream>>>(part1, accb1);
        k_ff1<<<B * 32, 256, 0, stream>>>(ya, accb1, g1 + l * D, b1 + l * D,
                                          W1 + (size_t)l * F * D, bW1 + (size_t)l * F, t);
        k_ff2<<<B * 16, 256, 0, stream>>>(t, ya, accb1, g1 + l * D, b1 + l * D,
                                          W2 + (size_t)l * D * F, bW2 + (size_t)l * D, yb, part2);
        k_finalize<<<32, 256, 0, stream>>>(part2, accb2);
    }
    k_norm<<<B * S * D / 256, 256, 0, stream>>>(yb, accb2, g2 + 5 * D, b2 + 5 * D, (float*)d_out);
}

// Round 6
// 665.303 us; speedup vs baseline: 1.7527x; 1.4404x over previous
//
#include <hip/hip_runtime.h>
#include <hip/hip_bf16.h>
#include <float.h>
#include <math.h>

#define B 32
#define NN 999
#define S 1000
#define D 128
#define F 512
#define L 6
#define EPSN 1e-5f
#define WSTR 180224   // per-layer bf16 weight stride: 3*16384 + 2*65536

typedef __attribute__((ext_vector_type(4))) float f32x4;
typedef __attribute__((ext_vector_type(4))) short s16x4;
typedef __attribute__((ext_vector_type(8))) short s16x8;

#if defined(__has_builtin)
#if __has_builtin(__builtin_amdgcn_mfma_f32_16x16x16bf16_1k)
#define HAVE_MFMA16 1
#endif
#if __has_builtin(__builtin_amdgcn_mfma_f32_16x16x32_bf16)
#define HAVE_MFMA32 1
#endif
#endif

#ifdef HAVE_MFMA16
#define MFMA16(a, b, c) __builtin_amdgcn_mfma_f32_16x16x16bf16_1k((a), (b), (c), 0, 0, 0)
#else
static __device__ __forceinline__ f32x4 mfma16_asm(s16x4 a, s16x4 b, f32x4 c) {
    asm volatile("v_mfma_f32_16x16x16_bf16 %0, %1, %2, %0\n\ts_nop 7\n\ts_nop 7"
                 : "+v"(c) : "v"(a), "v"(b));
    return c;
}
#define MFMA16(a, b, c) mfma16_asm((a), (b), (c))
#endif

#ifdef HAVE_MFMA32
#define MFMA32(a, b, c) __builtin_amdgcn_mfma_f32_16x16x32_bf16((a), (b), (c), 0, 0, 0)
#else
static __device__ __forceinline__ f32x4 mfma32_asm(s16x8 a, s16x8 b, f32x4 c) {
    asm volatile("v_mfma_f32_16x16x32_bf16 %0, %1, %2, %0\n\ts_nop 7\n\ts_nop 7"
                 : "+v"(c) : "v"(a), "v"(b));
    return c;
}
#define MFMA32(a, b, c) mfma32_asm((a), (b), (c))
#endif

__device__ __forceinline__ float n2n(float v) {
    if (v != v) return 0.f;
    if (isinf(v)) return v > 0.f ? FLT_MAX : -FLT_MAX;
    return v;
}

__device__ __forceinline__ unsigned short f2bf(float x) {
    unsigned u = __float_as_uint(x);
    return (unsigned short)((u + 0x7fffu + ((u >> 16) & 1u)) >> 16);
}

__device__ __forceinline__ float bf2f(unsigned short v) {
    return __uint_as_float(((unsigned)v) << 16);
}

// ---------------- one-time: weights -> bf16 ----------------
// layout per layer (stride WSTR): Wq 0, Wk 16384, Wv 32768, W1 49152, W2 114688
__global__ __launch_bounds__(256) void k_wprep(
        const float* __restrict__ Wq, const float* __restrict__ Wk,
        const float* __restrict__ Wv, const float* __restrict__ W1,
        const float* __restrict__ W2, unsigned short* __restrict__ wbf) {
    int bx = blockIdx.x, l = blockIdx.y;
    const float* src; int doff, off;
    if (bx < 8)       { src = Wq + (size_t)l * 16384; doff = 0;      off = bx * 2048; }
    else if (bx < 16) { src = Wk + (size_t)l * 16384; doff = 16384;  off = (bx - 8) * 2048; }
    else if (bx < 24) { src = Wv + (size_t)l * 16384; doff = 32768;  off = (bx - 16) * 2048; }
    else if (bx < 56) { src = W1 + (size_t)l * 65536; doff = 49152;  off = (bx - 24) * 2048; }
    else              { src = W2 + (size_t)l * 65536; doff = 114688; off = (bx - 56) * 2048; }
    int i = off + threadIdx.x * 8;
    float4 a4 = *(const float4*)(src + i);
    float4 b4 = *(const float4*)(src + i + 4);
    s16x8 p = {(short)f2bf(a4.x), (short)f2bf(a4.y), (short)f2bf(a4.z), (short)f2bf(a4.w),
               (short)f2bf(b4.x), (short)f2bf(b4.y), (short)f2bf(b4.z), (short)f2bf(b4.w)};
    *(s16x8*)(wbf + (size_t)l * WSTR + doff + i) = p;
}

// ---------------- one-time prep: dist -> bf16 padded ----------------
__global__ __launch_bounds__(256) void k_prep(
        const float* __restrict__ dist, unsigned short* __restrict__ nd) {
    int row = blockIdx.x;
    int col = threadIdx.x * 4;
    unsigned short* op = nd + (size_t)row * 1024 + col;
    if (col < 1000) {
        float4 v = *(const float4*)(dist + (size_t)row * 1000 + col);
        s16x4 p = {(short)f2bf(v.x), (short)f2bf(v.y), (short)f2bf(v.z), (short)f2bf(v.w)};
        *(s16x4*)op = p;
    } else {
        s16x4 z = {0, 0, 0, 0};
        *(s16x4*)op = z;
    }
}

__global__ __launch_bounds__(128) void k_embed(
        const float* __restrict__ depot, const float* __restrict__ node,
        const float* __restrict__ Wd, const float* __restrict__ bd,
        const float* __restrict__ Wn, const float* __restrict__ bn,
        float* __restrict__ x) {
    int row = blockIdx.x;
    int b = row / S, s = row % S;
    int d = threadIdx.x;
    float o;
    if (s == 0) {
        float x0 = depot[b * 2 + 0], x1 = depot[b * 2 + 1];
        o = Wd[d * 2 + 0] * x0 + Wd[d * 2 + 1] * x1 + bd[d];
    } else {
        const float* p = node + ((size_t)b * NN + (s - 1)) * 3;
        o = Wn[d * 3 + 0] * p[0] + Wn[d * 3 + 1] * p[1] + Wn[d * 3 + 2] * p[2] + bn[d];
    }
    x[(size_t)row * D + d] = o;
}

__global__ __launch_bounds__(128) void k_rowxform(
        float* __restrict__ x, const float* __restrict__ W,
        const float* __restrict__ bias, const int* __restrict__ flag, int mode) {
    int b = blockIdx.x;
    int d = threadIdx.x;
    __shared__ float row[D];
    int r = (mode == 0) ? 1 : (1 - flag[b]) * NN;
    float* xr = x + ((size_t)b * S + r) * D;
    row[d] = xr[d];
    __syncthreads();
    float acc = bias[d];
    for (int e = 0; e < D; e += 4) {
        const float4 w = *(const float4*)(W + (size_t)d * D + e);
        acc += w.x * row[e] + w.y * row[e + 1] + w.z * row[e + 2] + w.w * row[e + 3];
    }
    xr[d] = acc;
}

// ---------------- qkv: norm-fused input, bf16 weights, coalesced swizzled mT ----------------
__global__ __launch_bounds__(256) void k_qkv(
        const float* __restrict__ yprev, const float* __restrict__ part2, int hasnorm,
        const float* __restrict__ gp, const float* __restrict__ bp,
        const unsigned short* __restrict__ wl,
        unsigned short* __restrict__ sqb, unsigned short* __restrict__ mT) {
    int blk = blockIdx.x;
    int b = blk >> 4, rb = blk & 15;
    int s0 = rb * 64;
    int tid = threadIdx.x, lane = tid & 63, wid = tid >> 6;
    __shared__ __align__(16) unsigned short lds[18432];  // xs[64*40]+wt[3][128*40]; reused tile[256*72]
    __shared__ float nsc[128], nsh[128];
    __shared__ float accv[256];
    unsigned short* xs = lds;
    unsigned short* wt0 = lds + 2560;

    if (hasnorm) {
        int st = tid >> 7, d = tid & 127;
        float s = 0.f;
#pragma unroll
        for (int c = 0; c < 16; c++) s += part2[(size_t)(b * 32 + c * 2 + st) * 128 + d];
        accv[tid] = s;
    }
    __syncthreads();
    if (tid < 128) {
        float scv = 1.f, shv = 0.f;
        if (hasnorm) {
            float mu = accv[tid] * (1.f / S);
            float var = accv[128 + tid] * (1.f / S) - mu * mu;
            float rs = rsqrtf(var + EPSN);
            scv = rs * gp[tid];
            shv = bp[tid] - mu * scv;
        }
        nsc[tid] = scv; nsh[tid] = shv;
    }
    __syncthreads();

    f32x4 acc[3][8];
#pragma unroll
    for (int mm = 0; mm < 3; mm++)
#pragma unroll
        for (int cf = 0; cf < 8; cf++) acc[mm][cf] = {0.f, 0.f, 0.f, 0.f};

    for (int k0 = 0; k0 < D; k0 += 32) {
        {
            int i = tid >> 2, kq = (tid & 3) * 8;
            int s = s0 + i;
            int gs = s < S ? s : S - 1;
            const float* gpx = yprev + ((size_t)b * S + gs) * D + k0 + kq;
            float4 a4 = *(const float4*)gpx;
            float4 b4 = *(const float4*)(gpx + 4);
            const float* scp = &nsc[k0 + kq];
            const float* shp = &nsh[k0 + kq];
            s16x4 p0 = {(short)f2bf(a4.x * scp[0] + shp[0]), (short)f2bf(a4.y * scp[1] + shp[1]),
                        (short)f2bf(a4.z * scp[2] + shp[2]), (short)f2bf(a4.w * scp[3] + shp[3])};
            s16x4 p1 = {(short)f2bf(b4.x * scp[4] + shp[4]), (short)f2bf(b4.y * scp[5] + shp[5]),
                        (short)f2bf(b4.z * scp[6] + shp[6]), (short)f2bf(b4.w * scp[7] + shp[7])};
            *(s16x4*)&xs[i * 40 + kq] = p0;
            *(s16x4*)&xs[i * 40 + kq + 4] = p1;
        }
#pragma unroll
        for (int u0 = 0; u0 < 6; u0++) {
            int u = tid + u0 * 256;
            int mm = u >> 9;
            int v = u & 511;
            int c = v >> 2, kq = (v & 3) * 8;
            s16x8 w = *(const s16x8*)(wl + (size_t)mm * 16384 + (size_t)c * D + k0 + kq);
            *(s16x8*)&wt0[mm * 5120 + c * 40 + kq] = w;
        }
        __syncthreads();
#pragma unroll
        for (int ks = 0; ks < 2; ks++) {
            int ko = ks * 16 + (lane >> 4) * 4;
            s16x4 a = *(const s16x4*)&xs[(wid * 16 + (lane & 15)) * 40 + ko];
#pragma unroll
            for (int mm = 0; mm < 3; mm++)
#pragma unroll
                for (int cf = 0; cf < 8; cf++) {
                    s16x4 bf = *(const s16x4*)&wt0[mm * 5120 + (cf * 16 + (lane & 15)) * 40 + ko];
                    acc[mm][cf] = MFMA16(a, bf, acc[mm][cf]);
                }
        }
        __syncthreads();
    }

    // epilogue phase 1: acc -> tile[256 d][72]  (stride 72 shorts = 144 B, 16B-aligned rows)
    unsigned short* tile = lds;               // 256*72 = 18432
    int sl0 = wid * 16 + (lane >> 4) * 4;     // local k
#pragma unroll
    for (int cf = 0; cf < 8; cf++) {
        int d = cf * 16 + (lane & 15);
        s16x4 p0, p1;
#pragma unroll
        for (int r = 0; r < 4; r++) {
            int s = s0 + sl0 + r;
            if (s < S) {
                float qv = acc[0][cf][r], kv = acc[1][cf][r], vv = acc[2][cf][r];
                float ek = __expf(kv);
                sqb[((size_t)b * S + s) * D + d] = f2bf(1.f / (1.f + __expf(-qv)));
                p0[r] = (short)f2bf(ek * vv);
                p1[r] = (short)f2bf(ek);
            } else { p0[r] = 0; p1[r] = 0; }
        }
        *(s16x4*)&tile[d * 72 + sl0] = p0;
        *(s16x4*)&tile[(d + 128) * 72 + sl0] = p1;
    }
    __syncthreads();
    // epilogue phase 2: permuted read, fully coalesced 32KB store
    {
        unsigned short* base = mT + (((size_t)b * 16 + rb) * 256) * 64;
#pragma unroll
        for (int j = 0; j < 8; j++) {
            int u = j * 256 + tid;
            int d = u >> 3, sp = u & 7;
            int o = sp ^ (d & 7);
            s16x8 v = *(const s16x8*)&tile[d * 72 + o * 8];
            *(s16x8*)(base + (size_t)u * 8) = v;
        }
    }
}

// ---------------- attention: pipelined reg-staging, fused residual-norm + stats ----------------
__global__ __launch_bounds__(256) void k_attn(
        const float* __restrict__ yprev, const float* __restrict__ part2, int hasnorm,
        const float* __restrict__ gp, const float* __restrict__ bp,
        const unsigned short* __restrict__ sqb,
        const unsigned short* __restrict__ mT, const unsigned short* __restrict__ nd,
        const float* __restrict__ log_scale, const float* __restrict__ alpha, int l,
        float* __restrict__ y, float* __restrict__ part) {
    int blk0 = blockIdx.x;
    int blk = (blk0 & 7) * 64 + (blk0 >> 3);  // XCD-bijective swizzle (512 % 8 == 0)
    int b = blk >> 4, ib = blk & 15;
    int i0 = ib * 64;
    int tid = threadIdx.x, lane = tid & 63, wid = tid >> 6;
    __shared__ __align__(16) unsigned short esL[64 * 64];
    __shared__ __align__(16) unsigned short mtL[256 * 64];
    __shared__ float accvA[256];
    float sc = log_scale[0] * alpha[l];

    if (hasnorm) {
        int st = tid >> 7, d = tid & 127;
        float s = 0.f;
#pragma unroll
        for (int c = 0; c < 16; c++) s += part2[(size_t)(b * 32 + c * 2 + st) * 128 + d];
        accvA[tid] = s;
    }
    __syncthreads();

    float rsc[8], rsh[8];
#pragma unroll
    for (int cf = 0; cf < 8; cf++) {
        int d = cf * 16 + (lane & 15);
        float scv = 1.f, shv = 0.f;
        if (hasnorm) {
            float mu = accvA[d] * (1.f / S);
            float var = accvA[128 + d] * (1.f / S) - mu * mu;
            float rs = rsqrtf(var + EPSN);
            scv = rs * gp[d];
            shv = bp[d] - mu * scv;
        }
        rsc[cf] = scv; rsh[cf] = shv;
    }

    f32x4 acc[16];
#pragma unroll
    for (int cf = 0; cf < 16; cf++) acc[cf] = {0.f, 0.f, 0.f, 0.f};

    int erow = tid >> 2;
    int gi = i0 + erow; if (gi > 999) gi = 999;
    const unsigned short* ndr = nd + (size_t)b * 1000 * 1024 + (size_t)gi * 1024 + (tid & 3) * 16;
    const unsigned short* mtb = mT + (size_t)b * 16 * 16384;
    int eg = (tid & 3) * 2;
    unsigned short* esw0 = &esL[erow * 64 + ((eg) ^ (erow & 7)) * 8];
    unsigned short* esw1 = &esL[erow * 64 + ((eg + 1) ^ (erow & 7)) * 8];

    s16x8 cnA = *(const s16x8*)(ndr);
    s16x8 cnB = *(const s16x8*)(ndr + 8);
    s16x8 cm[8];
#pragma unroll
    for (int i2 = 0; i2 < 8; i2++)
        cm[i2] = *(const s16x8*)(mtb + (size_t)(i2 * 256 + tid) * 8);

    for (int kc = 0; kc < 16; kc++) {
        s16x8 o0, o1;
#pragma unroll
        for (int j = 0; j < 8; j++) {
            o0[j] = (short)f2bf(__expf(-sc * bf2f((unsigned short)cnA[j])));
            o1[j] = (short)f2bf(__expf(-sc * bf2f((unsigned short)cnB[j])));
        }
        int kn = kc < 15 ? kc + 1 : 15;
        cnA = *(const s16x8*)(ndr + kn * 64);
        cnB = *(const s16x8*)(ndr + kn * 64 + 8);
        __syncthreads();
        *(s16x8*)esw0 = o0;
        *(s16x8*)esw1 = o1;
#pragma unroll
        for (int i2 = 0; i2 < 8; i2++)
            *(s16x8*)&mtL[(i2 * 256 + tid) * 8] = cm[i2];
#pragma unroll
        for (int i2 = 0; i2 < 8; i2++)
            cm[i2] = *(const s16x8*)(mtb + (size_t)kn * 16384 + (size_t)(i2 * 256 + tid) * 8);
        __syncthreads();
#pragma unroll
        for (int ks = 0; ks < 2; ks++) {
            int arow = wid * 16 + (lane & 15);
            int ag = ks * 4 + (lane >> 4);
            s16x8 a = *(const s16x8*)&esL[arow * 64 + ((ag ^ (arow & 7)) * 8)];
            __builtin_amdgcn_s_setprio(1);
#pragma unroll
            for (int cf = 0; cf < 16; cf++) {
                int c = (cf & 7) * 16 + (cf >> 3) * 128 + (lane & 15);
                s16x8 bf = *(const s16x8*)&mtL[c * 64 + ((ag ^ (c & 7)) * 8)];
                acc[cf] = MFMA32(a, bf, acc[cf]);
            }
            __builtin_amdgcn_s_setprio(0);
        }
    }

    __syncthreads();
    float* pw = (float*)mtL;
#pragma unroll
    for (int cf = 0; cf < 8; cf++) {
        int d = cf * 16 + (lane & 15);
        float s = 0.f, s2 = 0.f;
#pragma unroll
        for (int r = 0; r < 4; r++) {
            int i = i0 + wid * 16 + (lane >> 4) * 4 + r;
            if (i < S) {
                size_t off = ((size_t)b * S + i) * D + d;
                float w = n2n(acc[cf][r]) / n2n(acc[cf + 8][r]);
                float xv = yprev[off] * rsc[cf] + rsh[cf];
                float yv = xv + bf2f(sqb[off]) * w;
                y[off] = yv;
                s += yv;
                s2 = fmaf(yv, yv, s2);
            }
        }
        s += __shfl_xor(s, 16); s += __shfl_xor(s, 32);
        s2 += __shfl_xor(s2, 16); s2 += __shfl_xor(s2, 32);
        if (lane < 16) {
            pw[(wid * 2 + 0) * 128 + d] = s;
            pw[(wid * 2 + 1) * 128 + d] = s2;
        }
    }
    __syncthreads();
    {
        int st = tid >> 7, d = tid & 127;
        float v = pw[(0 * 2 + st) * 128 + d] + pw[(1 * 2 + st) * 128 + d] +
                  pw[(2 * 2 + st) * 128 + d] + pw[(3 * 2 + st) * 128 + d];
        part[((size_t)(b * 16 + ib) * 2 + st) * 128 + d] = v;
    }
}

// ---------------- fused FFN: norm(part1) -> relu(h@W1^T+b) in LDS -> @W2^T + residual ----------------
__global__ __launch_bounds__(256) void k_ffn(
        const float* __restrict__ ya, const float* __restrict__ part1,
        const float* __restrict__ gp, const float* __restrict__ bp,
        const unsigned short* __restrict__ w1b, const unsigned short* __restrict__ w2b,
        const float* __restrict__ bW1, const float* __restrict__ bW2,
        float* __restrict__ yb, float* __restrict__ part) {
    int blk = blockIdx.x;
    int b = blk >> 4, rb = blk & 15;
    int r0 = rb * 64;
    int tid = threadIdx.x, lane = tid & 63, wid = tid >> 6;
    __shared__ __align__(16) unsigned short hs[64 * 128];    // normed h bf16, octet-swizzled
    __shared__ __align__(16) unsigned short w1c[64 * 128];   // W1 chunk [64 f][128 k], swizzled
    __shared__ __align__(16) unsigned short tc[64 * 72];     // t chunk [64 row][64 f], stride 144B
    __shared__ __align__(16) unsigned short w2c[128 * 64];   // W2 chunk [128 d][64 f], swizzled
    __shared__ float nsc[128], nsh[128];
    __shared__ float accv[256];

    {
        int st = tid >> 7, d = tid & 127;
        float s = 0.f;
#pragma unroll
        for (int c = 0; c < 16; c++) s += part1[(size_t)(b * 32 + c * 2 + st) * 128 + d];
        accv[tid] = s;
    }
    __syncthreads();
    if (tid < 128) {
        float mu = accv[tid] * (1.f / S);
        float var = accv[128 + tid] * (1.f / S) - mu * mu;
        float rs = rsqrtf(var + EPSN);
        float scv = rs * gp[tid];
        nsc[tid] = scv;
        nsh[tid] = bp[tid] - mu * scv;
    }
    __syncthreads();

    // stage normed h (64 rows x 128 k), octet-swizzled
    {
        int i = tid >> 2;
        int gs = r0 + i; if (gs >= S) gs = S - 1;
        const float* gpx = ya + ((size_t)b * S + gs) * D;
#pragma unroll
        for (int q = 0; q < 4; q++) {
            int col = (tid & 3) * 32 + q * 8;
            int g = col >> 3;
            float4 a4 = *(const float4*)(gpx + col);
            float4 b4 = *(const float4*)(gpx + col + 4);
            const float* scp = &nsc[col];
            const float* shp = &nsh[col];
            s16x4 p0 = {(short)f2bf(a4.x * scp[0] + shp[0]), (short)f2bf(a4.y * scp[1] + shp[1]),
                        (short)f2bf(a4.z * scp[2] + shp[2]), (short)f2bf(a4.w * scp[3] + shp[3])};
            s16x4 p1 = {(short)f2bf(b4.x * scp[4] + shp[4]), (short)f2bf(b4.y * scp[5] + shp[5]),
                        (short)f2bf(b4.z * scp[6] + shp[6]), (short)f2bf(b4.w * scp[7] + shp[7])};
            int base = i * 128 + ((g ^ (i & 7)) * 8);
            *(s16x4*)&hs[base] = p0;
            *(s16x4*)&hs[base + 4] = p1;
        }
    }

    f32x4 yacc[8];
#pragma unroll
    for (int cf = 0; cf < 8; cf++) yacc[cf] = {0.f, 0.f, 0.f, 0.f};

    for (int fc = 0; fc < 8; fc++) {
        int c0 = fc * 64;
        // stage W1 chunk [64 f][128 k], swizzled
        {
            int f = tid >> 2;
#pragma unroll
            for (int q = 0; q < 4; q++) {
                int col = (tid & 3) * 32 + q * 8;
                int g = col >> 3;
                s16x8 w = *(const s16x8*)(w1b + (size_t)(c0 + f) * D + col);
                *(s16x8*)&w1c[f * 128 + ((g ^ (f & 7)) * 8)] = w;
            }
        }
        // stage W2 chunk [128 d][64 f], swizzled
        {
            int d2 = tid >> 1;
#pragma unroll
            for (int q = 0; q < 4; q++) {
                int g = (tid & 1) * 4 + q;
                s16x8 w = *(const s16x8*)(w2b + (size_t)d2 * F + c0 + g * 8);
                *(s16x8*)&w2c[d2 * 64 + ((g ^ (d2 & 7)) * 8)] = w;
            }
        }
        __syncthreads();
        // GEMM1: t = relu(h @ W1c^T + bW1)
        f32x4 tacc[4];
#pragma unroll
        for (int c4 = 0; c4 < 4; c4++) tacc[c4] = {0.f, 0.f, 0.f, 0.f};
#pragma unroll
        for (int ks = 0; ks < 4; ks++) {
            int g = ks * 4 + (lane >> 4);
            int arow = wid * 16 + (lane & 15);
            s16x8 a = *(const s16x8*)&hs[arow * 128 + ((g ^ (arow & 7)) * 8)];
#pragma unroll
            for (int c4 = 0; c4 < 4; c4++) {
                int brow = c4 * 16 + (lane & 15);
                s16x8 bf = *(const s16x8*)&w1c[brow * 128 + ((g ^ (brow & 7)) * 8)];
                tacc[c4] = MFMA32(a, bf, tacc[c4]);
            }
        }
#pragma unroll
        for (int c4 = 0; c4 < 4; c4++) {
            int col = c4 * 16 + (lane & 15);
            float bias = bW1[c0 + col];
#pragma unroll
            for (int r = 0; r < 4; r++) {
                int rl = wid * 16 + (lane >> 4) * 4 + r;
                tc[rl * 72 + col] = f2bf(fmaxf(tacc[c4][r] + bias, 0.f));
            }
        }
        __syncthreads();
        // GEMM2: yacc += t @ W2c^T
#pragma unroll
        for (int ks = 0; ks < 2; ks++) {
            int ko = ks * 32 + (lane >> 4) * 8;
            int g = ks * 4 + (lane >> 4);
            s16x8 a = *(const s16x8*)&tc[(wid * 16 + (lane & 15)) * 72 + ko];
#pragma unroll
            for (int cf = 0; cf < 8; cf++) {
                int brow = cf * 16 + (lane & 15);
                s16x8 bf = *(const s16x8*)&w2c[brow * 64 + ((g ^ (brow & 7)) * 8)];
                yacc[cf] = MFMA32(a, bf, yacc[cf]);
            }
        }
        __syncthreads();
    }

    // epilogue: yb = h + ff + bias, stats
    float* pw = (float*)w1c;
#pragma unroll
    for (int cf = 0; cf < 8; cf++) {
        int d = cf * 16 + (lane & 15);
        float bias = bW2[d];
        float s = 0.f, s2 = 0.f;
#pragma unroll
        for (int r = 0; r < 4; r++) {
            int rl = wid * 16 + (lane >> 4) * 4 + r;
            int row = r0 + rl;
            if (row < S) {
                float hval = bf2f(hs[rl * 128 + (((d >> 3) ^ (rl & 7)) * 8) + (d & 7)]);
                float yv = hval + yacc[cf][r] + bias;
                yb[((size_t)b * S + row) * D + d] = yv;
                s += yv;
                s2 = fmaf(yv, yv, s2);
            }
        }
        s += __shfl_xor(s, 16); s += __shfl_xor(s, 32);
        s2 += __shfl_xor(s2, 16); s2 += __shfl_xor(s2, 32);
        if (lane < 16) {
            pw[(wid * 2 + 0) * 128 + d] = s;
            pw[(wid * 2 + 1) * 128 + d] = s2;
        }
    }
    __syncthreads();
    {
        int st = tid >> 7, d = tid & 127;
        float v = pw[(0 * 2 + st) * 128 + d] + pw[(1 * 2 + st) * 128 + d] +
                  pw[(2 * 2 + st) * 128 + d] + pw[(3 * 2 + st) * 128 + d];
        part[((size_t)(b * 16 + rb) * 2 + st) * 128 + d] = v;
    }
}

// ---------------- final reduce + norm ----------------
__global__ __launch_bounds__(256) void k_finalize(
        const float* __restrict__ part, float* __restrict__ acc) {
    int i = blockIdx.x * 256 + threadIdx.x;
    int b = i >> 8, k = i & 255;
    float s = 0.f;
#pragma unroll
    for (int c = 0; c < 16; c++) s += part[(size_t)(b * 16 + c) * 256 + k];
    acc[i] = s;
}

__global__ __launch_bounds__(256) void k_norm(
        const float* __restrict__ y, const float* __restrict__ acc,
        const float* __restrict__ g, const float* __restrict__ bb,
        float* __restrict__ out) {
    size_t i = (size_t)blockIdx.x * 256 + threadIdx.x;
    int d = (int)(i % D);
    int b = (int)(i / ((size_t)S * D));
    float mu = acc[b * 256 + d] * (1.f / S);
    float var = acc[b * 256 + 128 + d] * (1.f / S) - mu * mu;
    float v = (y[i] - mu) * rsqrtf(var + EPSN);
    out[i] = v * g[d] + bb[d];
}

extern "C" void kernel_launch(void* const* d_in, const int* in_sizes, int n_in,
                              void* d_out, int out_size, void* d_ws, size_t ws_size,
                              hipStream_t stream) {
    const float* depot = (const float*)d_in[0];
    const float* node  = (const float*)d_in[1];
    const float* dist  = (const float*)d_in[2];
    const float* log_scale = (const float*)d_in[3];
    const int*   flag  = (const int*)d_in[4];
    const float* Wd   = (const float*)d_in[5];
    const float* bd   = (const float*)d_in[6];
    const float* Wn   = (const float*)d_in[7];
    const float* bn   = (const float*)d_in[8];
    const float* Win  = (const float*)d_in[9];
    const float* bin_ = (const float*)d_in[10];
    const float* Wout = (const float*)d_in[11];
    const float* bout = (const float*)d_in[12];
    const float* Wq   = (const float*)d_in[13];
    const float* Wk   = (const float*)d_in[14];
    const float* Wv   = (const float*)d_in[15];
    const float* alpha= (const float*)d_in[16];
    const float* g1   = (const float*)d_in[17];
    const float* b1   = (const float*)d_in[18];
    const float* W1   = (const float*)d_in[19];
    const float* bW1  = (const float*)d_in[20];
    const float* W2   = (const float*)d_in[21];
    const float* bW2  = (const float*)d_in[22];
    const float* g2   = (const float*)d_in[23];
    const float* b2   = (const float*)d_in[24];

    float* ws = (float*)d_ws;
    size_t nxd = (size_t)B * S * D;                       // 4,096,000
    float* ya    = ws;
    float* yb    = ws + nxd;
    float* part1 = ws + 2 * nxd;                          // B*16*256 = 131072
    float* part2 = part1 + 131072;
    float* accb2 = part2 + 131072;                        // B*256
    unsigned short* sqb = (unsigned short*)(accb2 + 8192);          // B*S*D bf16
    unsigned short* mT  = sqb + nxd;                                // B*16*256*64
    unsigned short* wbf = mT + (size_t)B * 16 * 256 * 64;           // L*WSTR
    unsigned short* nd  = wbf + (size_t)L * WSTR;                   // B*1000*1024

    k_wprep<<<dim3(88, 6), 256, 0, stream>>>(Wq, Wk, Wv, W1, W2, wbf);
    k_prep<<<B * S, 256, 0, stream>>>(dist, nd);
    k_embed<<<B * S, 128, 0, stream>>>(depot, node, Wd, bd, Wn, bn, yb);
    k_rowxform<<<B, 128, 0, stream>>>(yb, Win, bin_, flag, 0);
    k_rowxform<<<B, 128, 0, stream>>>(yb, Wout, bout, flag, 1);

    for (int l = 0; l < L; l++) {
        int hasnorm = (l > 0) ? 1 : 0;
        const float* gpn = g2 + (l > 0 ? (l - 1) : 0) * D;
        const float* bpn = b2 + (l > 0 ? (l - 1) : 0) * D;
        const unsigned short* wl = wbf + (size_t)l * WSTR;
        k_qkv<<<B * 16, 256, 0, stream>>>(yb, part2, hasnorm, gpn, bpn, wl, sqb, mT);
        k_attn<<<B * 16, 256, 0, stream>>>(yb, part2, hasnorm, gpn, bpn,
                                           sqb, mT, nd, log_scale, alpha, l, ya, part1);
        k_ffn<<<B * 16, 256, 0, stream>>>(ya, part1, g1 + l * D, b1 + l * D,
                                          wl + 49152, wl + 114688,
                                          bW1 + (size_t)l * F, bW2 + (size_t)l * D, yb, part2);
    }
    k_finalize<<<32, 256, 0, stream>>>(part2, accb2);
    k_norm<<<B * S * D / 256, 256, 0, stream>>>(yb, accb2, g2 + 5 * D, b2 + 5 * D, (float*)d_out);
}

// Round 7
// 642.979 us; speedup vs baseline: 1.8135x; 1.0347x over previous
//
#include <hip/hip_runtime.h>
#include <hip/hip_bf16.h>
#include <float.h>
#include <math.h>

#define B 32
#define NN 999
#define S 1000
#define D 128
#define F 512
#define L 6
#define EPSN 1e-5f
#define WSTR 180224   // per-layer bf16 weight stride: 3*16384 + 2*65536

typedef __attribute__((ext_vector_type(4))) float f32x4;
typedef __attribute__((ext_vector_type(4))) short s16x4;
typedef __attribute__((ext_vector_type(8))) short s16x8;

#if defined(__has_builtin)
#if __has_builtin(__builtin_amdgcn_mfma_f32_16x16x16bf16_1k)
#define HAVE_MFMA16 1
#endif
#if __has_builtin(__builtin_amdgcn_mfma_f32_16x16x32_bf16)
#define HAVE_MFMA32 1
#endif
#endif

#ifdef HAVE_MFMA16
#define MFMA16(a, b, c) __builtin_amdgcn_mfma_f32_16x16x16bf16_1k((a), (b), (c), 0, 0, 0)
#else
static __device__ __forceinline__ f32x4 mfma16_asm(s16x4 a, s16x4 b, f32x4 c) {
    asm volatile("v_mfma_f32_16x16x16_bf16 %0, %1, %2, %0\n\ts_nop 7\n\ts_nop 7"
                 : "+v"(c) : "v"(a), "v"(b));
    return c;
}
#define MFMA16(a, b, c) mfma16_asm((a), (b), (c))
#endif

#ifdef HAVE_MFMA32
#define MFMA32(a, b, c) __builtin_amdgcn_mfma_f32_16x16x32_bf16((a), (b), (c), 0, 0, 0)
#else
static __device__ __forceinline__ f32x4 mfma32_asm(s16x8 a, s16x8 b, f32x4 c) {
    asm volatile("v_mfma_f32_16x16x32_bf16 %0, %1, %2, %0\n\ts_nop 7\n\ts_nop 7"
                 : "+v"(c) : "v"(a), "v"(b));
    return c;
}
#define MFMA32(a, b, c) mfma32_asm((a), (b), (c))
#endif

__device__ __forceinline__ float n2n(float v) {
    if (v != v) return 0.f;
    if (isinf(v)) return v > 0.f ? FLT_MAX : -FLT_MAX;
    return v;
}

__device__ __forceinline__ unsigned short f2bf(float x) {
    unsigned u = __float_as_uint(x);
    return (unsigned short)((u + 0x7fffu + ((u >> 16) & 1u)) >> 16);
}

__device__ __forceinline__ float bf2f(unsigned short v) {
    return __uint_as_float(((unsigned)v) << 16);
}

// ---------------- one-time: weights -> bf16 ----------------
// layout per layer (stride WSTR): Wq 0, Wk 16384, Wv 32768, W1 49152, W2 114688
__global__ __launch_bounds__(256) void k_wprep(
        const float* __restrict__ Wq, const float* __restrict__ Wk,
        const float* __restrict__ Wv, const float* __restrict__ W1,
        const float* __restrict__ W2, unsigned short* __restrict__ wbf) {
    int bx = blockIdx.x, l = blockIdx.y;
    const float* src; int doff, off;
    if (bx < 8)       { src = Wq + (size_t)l * 16384; doff = 0;      off = bx * 2048; }
    else if (bx < 16) { src = Wk + (size_t)l * 16384; doff = 16384;  off = (bx - 8) * 2048; }
    else if (bx < 24) { src = Wv + (size_t)l * 16384; doff = 32768;  off = (bx - 16) * 2048; }
    else if (bx < 56) { src = W1 + (size_t)l * 65536; doff = 49152;  off = (bx - 24) * 2048; }
    else              { src = W2 + (size_t)l * 65536; doff = 114688; off = (bx - 56) * 2048; }
    int i = off + threadIdx.x * 8;
    float4 a4 = *(const float4*)(src + i);
    float4 b4 = *(const float4*)(src + i + 4);
    s16x8 p = {(short)f2bf(a4.x), (short)f2bf(a4.y), (short)f2bf(a4.z), (short)f2bf(a4.w),
               (short)f2bf(b4.x), (short)f2bf(b4.y), (short)f2bf(b4.z), (short)f2bf(b4.w)};
    *(s16x8*)(wbf + (size_t)l * WSTR + doff + i) = p;
}

// ---------------- one-time prep: dist -> bf16 padded ----------------
__global__ __launch_bounds__(256) void k_prep(
        const float* __restrict__ dist, unsigned short* __restrict__ nd) {
    int row = blockIdx.x;
    int col = threadIdx.x * 4;
    unsigned short* op = nd + (size_t)row * 1024 + col;
    if (col < 1000) {
        float4 v = *(const float4*)(dist + (size_t)row * 1000 + col);
        s16x4 p = {(short)f2bf(v.x), (short)f2bf(v.y), (short)f2bf(v.z), (short)f2bf(v.w)};
        *(s16x4*)op = p;
    } else {
        s16x4 z = {0, 0, 0, 0};
        *(s16x4*)op = z;
    }
}

__global__ __launch_bounds__(128) void k_embed(
        const float* __restrict__ depot, const float* __restrict__ node,
        const float* __restrict__ Wd, const float* __restrict__ bd,
        const float* __restrict__ Wn, const float* __restrict__ bn,
        float* __restrict__ x) {
    int row = blockIdx.x;
    int b = row / S, s = row % S;
    int d = threadIdx.x;
    float o;
    if (s == 0) {
        float x0 = depot[b * 2 + 0], x1 = depot[b * 2 + 1];
        o = Wd[d * 2 + 0] * x0 + Wd[d * 2 + 1] * x1 + bd[d];
    } else {
        const float* p = node + ((size_t)b * NN + (s - 1)) * 3;
        o = Wn[d * 3 + 0] * p[0] + Wn[d * 3 + 1] * p[1] + Wn[d * 3 + 2] * p[2] + bn[d];
    }
    x[(size_t)row * D + d] = o;
}

__global__ __launch_bounds__(128) void k_rowxform(
        float* __restrict__ x, const float* __restrict__ W,
        const float* __restrict__ bias, const int* __restrict__ flag, int mode) {
    int b = blockIdx.x;
    int d = threadIdx.x;
    __shared__ float row[D];
    int r = (mode == 0) ? 1 : (1 - flag[b]) * NN;
    float* xr = x + ((size_t)b * S + r) * D;
    row[d] = xr[d];
    __syncthreads();
    float acc = bias[d];
    for (int e = 0; e < D; e += 4) {
        const float4 w = *(const float4*)(W + (size_t)d * D + e);
        acc += w.x * row[e] + w.y * row[e + 1] + w.z * row[e + 2] + w.w * row[e + 3];
    }
    xr[d] = acc;
}

// ---------------- qkv: norm-fused input, bf16 weights, coalesced swizzled mT ----------------
__global__ __launch_bounds__(256) void k_qkv(
        const float* __restrict__ yprev, const float* __restrict__ part2, int hasnorm,
        const float* __restrict__ gp, const float* __restrict__ bp,
        const unsigned short* __restrict__ wl,
        unsigned short* __restrict__ sqb, unsigned short* __restrict__ mT) {
    int blk = blockIdx.x;
    int b = blk >> 4, rb = blk & 15;
    int s0 = rb * 64;
    int tid = threadIdx.x, lane = tid & 63, wid = tid >> 6;
    __shared__ __align__(16) unsigned short lds[18432];  // xs[64*40]+wt[3][128*40]; reused tile[256*72]
    __shared__ float nsc[128], nsh[128];
    __shared__ float accv[256];
    unsigned short* xs = lds;
    unsigned short* wt0 = lds + 2560;

    if (hasnorm) {
        int st = tid >> 7, d = tid & 127;
        float s = 0.f;
#pragma unroll
        for (int c = 0; c < 16; c++) s += part2[(size_t)(b * 32 + c * 2 + st) * 128 + d];
        accv[tid] = s;
    }
    __syncthreads();
    if (tid < 128) {
        float scv = 1.f, shv = 0.f;
        if (hasnorm) {
            float mu = accv[tid] * (1.f / S);
            float var = accv[128 + tid] * (1.f / S) - mu * mu;
            float rs = rsqrtf(var + EPSN);
            scv = rs * gp[tid];
            shv = bp[tid] - mu * scv;
        }
        nsc[tid] = scv; nsh[tid] = shv;
    }
    __syncthreads();

    f32x4 acc[3][8];
#pragma unroll
    for (int mm = 0; mm < 3; mm++)
#pragma unroll
        for (int cf = 0; cf < 8; cf++) acc[mm][cf] = {0.f, 0.f, 0.f, 0.f};

    for (int k0 = 0; k0 < D; k0 += 32) {
        {
            int i = tid >> 2, kq = (tid & 3) * 8;
            int s = s0 + i;
            int gs = s < S ? s : S - 1;
            const float* gpx = yprev + ((size_t)b * S + gs) * D + k0 + kq;
            float4 a4 = *(const float4*)gpx;
            float4 b4 = *(const float4*)(gpx + 4);
            const float* scp = &nsc[k0 + kq];
            const float* shp = &nsh[k0 + kq];
            s16x4 p0 = {(short)f2bf(a4.x * scp[0] + shp[0]), (short)f2bf(a4.y * scp[1] + shp[1]),
                        (short)f2bf(a4.z * scp[2] + shp[2]), (short)f2bf(a4.w * scp[3] + shp[3])};
            s16x4 p1 = {(short)f2bf(b4.x * scp[4] + shp[4]), (short)f2bf(b4.y * scp[5] + shp[5]),
                        (short)f2bf(b4.z * scp[6] + shp[6]), (short)f2bf(b4.w * scp[7] + shp[7])};
            *(s16x4*)&xs[i * 40 + kq] = p0;
            *(s16x4*)&xs[i * 40 + kq + 4] = p1;
        }
#pragma unroll
        for (int u0 = 0; u0 < 6; u0++) {
            int u = tid + u0 * 256;
            int mm = u >> 9;
            int v = u & 511;
            int c = v >> 2, kq = (v & 3) * 8;
            s16x8 w = *(const s16x8*)(wl + (size_t)mm * 16384 + (size_t)c * D + k0 + kq);
            *(s16x8*)&wt0[mm * 5120 + c * 40 + kq] = w;
        }
        __syncthreads();
#pragma unroll
        for (int ks = 0; ks < 2; ks++) {
            int ko = ks * 16 + (lane >> 4) * 4;
            s16x4 a = *(const s16x4*)&xs[(wid * 16 + (lane & 15)) * 40 + ko];
#pragma unroll
            for (int mm = 0; mm < 3; mm++)
#pragma unroll
                for (int cf = 0; cf < 8; cf++) {
                    s16x4 bf = *(const s16x4*)&wt0[mm * 5120 + (cf * 16 + (lane & 15)) * 40 + ko];
                    acc[mm][cf] = MFMA16(a, bf, acc[mm][cf]);
                }
        }
        __syncthreads();
    }

    // epilogue phase 1: acc -> tile[256 d][72]  (stride 72 shorts = 144 B, 16B-aligned rows)
    unsigned short* tile = lds;               // 256*72 = 18432
    int sl0 = wid * 16 + (lane >> 4) * 4;     // local k
#pragma unroll
    for (int cf = 0; cf < 8; cf++) {
        int d = cf * 16 + (lane & 15);
        s16x4 p0, p1;
#pragma unroll
        for (int r = 0; r < 4; r++) {
            int s = s0 + sl0 + r;
            if (s < S) {
                float qv = acc[0][cf][r], kv = acc[1][cf][r], vv = acc[2][cf][r];
                float ek = __expf(kv);
                sqb[((size_t)b * S + s) * D + d] = f2bf(1.f / (1.f + __expf(-qv)));
                p0[r] = (short)f2bf(ek * vv);
                p1[r] = (short)f2bf(ek);
            } else { p0[r] = 0; p1[r] = 0; }
        }
        *(s16x4*)&tile[d * 72 + sl0] = p0;
        *(s16x4*)&tile[(d + 128) * 72 + sl0] = p1;
    }
    __syncthreads();
    // epilogue phase 2: permuted read, fully coalesced 32KB store
    {
        unsigned short* base = mT + (((size_t)b * 16 + rb) * 256) * 64;
#pragma unroll
        for (int j = 0; j < 8; j++) {
            int u = j * 256 + tid;
            int d = u >> 3, sp = u & 7;
            int o = sp ^ (d & 7);
            s16x8 v = *(const s16x8*)&tile[d * 72 + o * 8];
            *(s16x8*)(base + (size_t)u * 8) = v;
        }
    }
}

// ---------------- attention: 8 waves (num/den split), pipelined reg-staging ----------------
__global__ __launch_bounds__(512, 2) void k_attn(
        const float* __restrict__ yprev, const float* __restrict__ part2, int hasnorm,
        const float* __restrict__ gp, const float* __restrict__ bp,
        const unsigned short* __restrict__ sqb,
        const unsigned short* __restrict__ mT, const unsigned short* __restrict__ nd,
        const float* __restrict__ log_scale, const float* __restrict__ alpha, int l,
        float* __restrict__ y, float* __restrict__ part) {
    int blk0 = blockIdx.x;
    int blk = (blk0 & 7) * 64 + (blk0 >> 3);  // XCD-bijective swizzle (512 % 8 == 0)
    int b = blk >> 4, ib = blk & 15;
    int i0 = ib * 64;
    int tid = threadIdx.x, lane = tid & 63, wid = tid >> 6;
    int wr = wid & 3, wh = wid >> 2;          // row group, cf half (0=num, 1=den)
    __shared__ __align__(16) unsigned short esL[64 * 64];   // 8 KB swizzled
    __shared__ __align__(16) unsigned short mtL[256 * 64];  // 32 KB; reused f32[64][128] for den
    __shared__ float accvA[256];
    float sc = log_scale[0] * alpha[l];

    if (hasnorm && tid < 256) {
        int st = tid >> 7, d = tid & 127;
        float s = 0.f;
#pragma unroll
        for (int c = 0; c < 16; c++) s += part2[(size_t)(b * 32 + c * 2 + st) * 128 + d];
        accvA[tid] = s;
    }
    __syncthreads();

    float rsc[8], rsh[8];
#pragma unroll
    for (int cf = 0; cf < 8; cf++) {
        int d = cf * 16 + (lane & 15);
        float scv = 1.f, shv = 0.f;
        if (hasnorm) {
            float mu = accvA[d] * (1.f / S);
            float var = accvA[128 + d] * (1.f / S) - mu * mu;
            float rs = rsqrtf(var + EPSN);
            scv = rs * gp[d];
            shv = bp[d] - mu * scv;
        }
        rsc[cf] = scv; rsh[cf] = shv;
    }

    f32x4 acc[8];
#pragma unroll
    for (int cf = 0; cf < 8; cf++) acc[cf] = {0.f, 0.f, 0.f, 0.f};

    // es staging: 1 octet/thread (row = tid>>3, octet og = tid&7)
    int erow = tid >> 3, og = tid & 7;
    int gi = i0 + erow; if (gi > 999) gi = 999;
    const unsigned short* ndr = nd + (size_t)b * 1000 * 1024 + (size_t)gi * 1024 + og * 8;
    const unsigned short* mtb = mT + (size_t)b * 16 * 16384;
    unsigned short* esw = &esL[erow * 64 + ((og ^ (erow & 7)) * 8)];

    s16x8 cn = *(const s16x8*)(ndr);
    s16x8 cm[4];
#pragma unroll
    for (int j = 0; j < 4; j++)
        cm[j] = *(const s16x8*)(mtb + (size_t)(j * 512 + tid) * 8);

    for (int kc = 0; kc < 16; kc++) {
        s16x8 o0;
#pragma unroll
        for (int j = 0; j < 8; j++)
            o0[j] = (short)f2bf(__expf(-sc * bf2f((unsigned short)cn[j])));
        int kn = kc < 15 ? kc + 1 : 15;
        cn = *(const s16x8*)(ndr + kn * 64);
        __syncthreads();
        *(s16x8*)esw = o0;
#pragma unroll
        for (int j = 0; j < 4; j++)
            *(s16x8*)&mtL[(j * 512 + tid) * 8] = cm[j];
#pragma unroll
        for (int j = 0; j < 4; j++)
            cm[j] = *(const s16x8*)(mtb + (size_t)kn * 16384 + (size_t)(j * 512 + tid) * 8);
        __syncthreads();
#pragma unroll
        for (int ks = 0; ks < 2; ks++) {
            int arow = wr * 16 + (lane & 15);
            int ag = ks * 4 + (lane >> 4);
            s16x8 a = *(const s16x8*)&esL[arow * 64 + ((ag ^ (arow & 7)) * 8)];
            __builtin_amdgcn_s_setprio(1);
#pragma unroll
            for (int cf = 0; cf < 8; cf++) {
                int c = cf * 16 + wh * 128 + (lane & 15);
                s16x8 bf = *(const s16x8*)&mtL[c * 64 + ((ag ^ (c & 7)) * 8)];
                acc[cf] = MFMA32(a, bf, acc[cf]);
            }
            __builtin_amdgcn_s_setprio(0);
        }
    }

    // epilogue: exchange den via LDS, then num waves finish
    __syncthreads();
    float* pw = (float*)mtL;                  // [64 rows][128 d] f32 = 32 KB
    if (wh == 1) {
#pragma unroll
        for (int cf = 0; cf < 8; cf++) {
            int c = cf * 16 + (lane & 15);
#pragma unroll
            for (int r = 0; r < 4; r++) {
                int rl = wr * 16 + (lane >> 4) * 4 + r;
                pw[rl * 128 + c] = acc[cf][r];
            }
        }
    }
    __syncthreads();
    float* sw = (float*)esL;                  // stats partials [8][128]
    if (wh == 0) {
#pragma unroll
        for (int cf = 0; cf < 8; cf++) {
            int d = cf * 16 + (lane & 15);
            float s = 0.f, s2 = 0.f;
#pragma unroll
            for (int r = 0; r < 4; r++) {
                int rl = wr * 16 + (lane >> 4) * 4 + r;
                int i = i0 + rl;
                if (i < S) {
                    size_t off = ((size_t)b * S + i) * D + d;
                    float w = n2n(acc[cf][r]) / n2n(pw[rl * 128 + d]);
                    float xv = yprev[off] * rsc[cf] + rsh[cf];
                    float yv = xv + bf2f(sqb[off]) * w;
                    y[off] = yv;
                    s += yv;
                    s2 = fmaf(yv, yv, s2);
                }
            }
            s += __shfl_xor(s, 16); s += __shfl_xor(s, 32);
            s2 += __shfl_xor(s2, 16); s2 += __shfl_xor(s2, 32);
            if (lane < 16) {
                sw[(wr * 2 + 0) * 128 + d] = s;
                sw[(wr * 2 + 1) * 128 + d] = s2;
            }
        }
    }
    __syncthreads();
    if (tid < 256) {
        int st = tid >> 7, d = tid & 127;
        float v = sw[(0 * 2 + st) * 128 + d] + sw[(1 * 2 + st) * 128 + d] +
                  sw[(2 * 2 + st) * 128 + d] + sw[(3 * 2 + st) * 128 + d];
        part[((size_t)(b * 16 + ib) * 2 + st) * 128 + d] = v;
    }
}

// ---------------- fused FFN: norm(part1) -> relu(h@W1^T+b) in LDS -> @W2^T + residual ----------------
__global__ __launch_bounds__(256) void k_ffn(
        const float* __restrict__ ya, const float* __restrict__ part1,
        const float* __restrict__ gp, const float* __restrict__ bp,
        const unsigned short* __restrict__ w1b, const unsigned short* __restrict__ w2b,
        const float* __restrict__ bW1, const float* __restrict__ bW2,
        float* __restrict__ yb, float* __restrict__ part) {
    int blk = blockIdx.x;
    int b = blk >> 4, rb = blk & 15;
    int r0 = rb * 64;
    int tid = threadIdx.x, lane = tid & 63, wid = tid >> 6;
    __shared__ __align__(16) unsigned short hs[64 * 128];    // normed h bf16, octet-swizzled
    __shared__ __align__(16) unsigned short w1c[64 * 128];   // W1 chunk [64 f][128 k], swizzled
    __shared__ __align__(16) unsigned short tc[64 * 72];     // t chunk [64 row][64 f], stride 144B
    __shared__ __align__(16) unsigned short w2c[128 * 64];   // W2 chunk [128 d][64 f], swizzled
    __shared__ float nsc[128], nsh[128];
    __shared__ float accv[256];

    {
        int st = tid >> 7, d = tid & 127;
        float s = 0.f;
#pragma unroll
        for (int c = 0; c < 16; c++) s += part1[(size_t)(b * 32 + c * 2 + st) * 128 + d];
        accv[tid] = s;
    }
    __syncthreads();
    if (tid < 128) {
        float mu = accv[tid] * (1.f / S);
        float var = accv[128 + tid] * (1.f / S) - mu * mu;
        float rs = rsqrtf(var + EPSN);
        float scv = rs * gp[tid];
        nsc[tid] = scv;
        nsh[tid] = bp[tid] - mu * scv;
    }
    __syncthreads();

    // stage normed h (64 rows x 128 k), octet-swizzled
    {
        int i = tid >> 2;
        int gs = r0 + i; if (gs >= S) gs = S - 1;
        const float* gpx = ya + ((size_t)b * S + gs) * D;
#pragma unroll
        for (int q = 0; q < 4; q++) {
            int col = (tid & 3) * 32 + q * 8;
            int g = col >> 3;
            float4 a4 = *(const float4*)(gpx + col);
            float4 b4 = *(const float4*)(gpx + col + 4);
            const float* scp = &nsc[col];
            const float* shp = &nsh[col];
            s16x4 p0 = {(short)f2bf(a4.x * scp[0] + shp[0]), (short)f2bf(a4.y * scp[1] + shp[1]),
                        (short)f2bf(a4.z * scp[2] + shp[2]), (short)f2bf(a4.w * scp[3] + shp[3])};
            s16x4 p1 = {(short)f2bf(b4.x * scp[4] + shp[4]), (short)f2bf(b4.y * scp[5] + shp[5]),
                        (short)f2bf(b4.z * scp[6] + shp[6]), (short)f2bf(b4.w * scp[7] + shp[7])};
            int base = i * 128 + ((g ^ (i & 7)) * 8);
            *(s16x4*)&hs[base] = p0;
            *(s16x4*)&hs[base + 4] = p1;
        }
    }

    f32x4 yacc[8];
#pragma unroll
    for (int cf = 0; cf < 8; cf++) yacc[cf] = {0.f, 0.f, 0.f, 0.f};

    for (int fc = 0; fc < 8; fc++) {
        int c0 = fc * 64;
        // stage W1 chunk [64 f][128 k], swizzled
        {
            int f = tid >> 2;
#pragma unroll
            for (int q = 0; q < 4; q++) {
                int col = (tid & 3) * 32 + q * 8;
                int g = col >> 3;
                s16x8 w = *(const s16x8*)(w1b + (size_t)(c0 + f) * D + col);
                *(s16x8*)&w1c[f * 128 + ((g ^ (f & 7)) * 8)] = w;
            }
        }
        // stage W2 chunk [128 d][64 f], swizzled
        {
            int d2 = tid >> 1;
#pragma unroll
            for (int q = 0; q < 4; q++) {
                int g = (tid & 1) * 4 + q;
                s16x8 w = *(const s16x8*)(w2b + (size_t)d2 * F + c0 + g * 8);
                *(s16x8*)&w2c[d2 * 64 + ((g ^ (d2 & 7)) * 8)] = w;
            }
        }
        __syncthreads();
        // GEMM1: t = relu(h @ W1c^T + bW1)
        f32x4 tacc[4];
#pragma unroll
        for (int c4 = 0; c4 < 4; c4++) tacc[c4] = {0.f, 0.f, 0.f, 0.f};
#pragma unroll
        for (int ks = 0; ks < 4; ks++) {
            int g = ks * 4 + (lane >> 4);
            int arow = wid * 16 + (lane & 15);
            s16x8 a = *(const s16x8*)&hs[arow * 128 + ((g ^ (arow & 7)) * 8)];
#pragma unroll
            for (int c4 = 0; c4 < 4; c4++) {
                int brow = c4 * 16 + (lane & 15);
                s16x8 bf = *(const s16x8*)&w1c[brow * 128 + ((g ^ (brow & 7)) * 8)];
                tacc[c4] = MFMA32(a, bf, tacc[c4]);
            }
        }
#pragma unroll
        for (int c4 = 0; c4 < 4; c4++) {
            int col = c4 * 16 + (lane & 15);
            float bias = bW1[c0 + col];
#pragma unroll
            for (int r = 0; r < 4; r++) {
                int rl = wid * 16 + (lane >> 4) * 4 + r;
                tc[rl * 72 + col] = f2bf(fmaxf(tacc[c4][r] + bias, 0.f));
            }
        }
        __syncthreads();
        // GEMM2: yacc += t @ W2c^T
#pragma unroll
        for (int ks = 0; ks < 2; ks++) {
            int ko = ks * 32 + (lane >> 4) * 8;
            int g = ks * 4 + (lane >> 4);
            s16x8 a = *(const s16x8*)&tc[(wid * 16 + (lane & 15)) * 72 + ko];
#pragma unroll
            for (int cf = 0; cf < 8; cf++) {
                int brow = cf * 16 + (lane & 15);
                s16x8 bf = *(const s16x8*)&w2c[brow * 64 + ((g ^ (brow & 7)) * 8)];
                yacc[cf] = MFMA32(a, bf, yacc[cf]);
            }
        }
        __syncthreads();
    }

    // epilogue: yb = h + ff + bias, stats
    float* pw = (float*)w1c;
#pragma unroll
    for (int cf = 0; cf < 8; cf++) {
        int d = cf * 16 + (lane & 15);
        float bias = bW2[d];
        float s = 0.f, s2 = 0.f;
#pragma unroll
        for (int r = 0; r < 4; r++) {
            int rl = wid * 16 + (lane >> 4) * 4 + r;
            int row = r0 + rl;
            if (row < S) {
                float hval = bf2f(hs[rl * 128 + (((d >> 3) ^ (rl & 7)) * 8) + (d & 7)]);
                float yv = hval + yacc[cf][r] + bias;
                yb[((size_t)b * S + row) * D + d] = yv;
                s += yv;
                s2 = fmaf(yv, yv, s2);
            }
        }
        s += __shfl_xor(s, 16); s += __shfl_xor(s, 32);
        s2 += __shfl_xor(s2, 16); s2 += __shfl_xor(s2, 32);
        if (lane < 16) {
            pw[(wid * 2 + 0) * 128 + d] = s;
            pw[(wid * 2 + 1) * 128 + d] = s2;
        }
    }
    __syncthreads();
    {
        int st = tid >> 7, d = tid & 127;
        float v = pw[(0 * 2 + st) * 128 + d] + pw[(1 * 2 + st) * 128 + d] +
                  pw[(2 * 2 + st) * 128 + d] + pw[(3 * 2 + st) * 128 + d];
        part[((size_t)(b * 16 + rb) * 2 + st) * 128 + d] = v;
    }
}

// ---------------- final reduce + norm ----------------
__global__ __launch_bounds__(256) void k_finalize(
        const float* __restrict__ part, float* __restrict__ acc) {
    int i = blockIdx.x * 256 + threadIdx.x;
    int b = i >> 8, k = i & 255;
    float s = 0.f;
#pragma unroll
    for (int c = 0; c < 16; c++) s += part[(size_t)(b * 16 + c) * 256 + k];
    acc[i] = s;
}

__global__ __launch_bounds__(256) void k_norm(
        const float* __restrict__ y, const float* __restrict__ acc,
        const float* __restrict__ g, const float* __restrict__ bb,
        float* __restrict__ out) {
    size_t i = (size_t)blockIdx.x * 256 + threadIdx.x;
    int d = (int)(i % D);
    int b = (int)(i / ((size_t)S * D));
    float mu = acc[b * 256 + d] * (1.f / S);
    float var = acc[b * 256 + 128 + d] * (1.f / S) - mu * mu;
    float v = (y[i] - mu) * rsqrtf(var + EPSN);
    out[i] = v * g[d] + bb[d];
}

extern "C" void kernel_launch(void* const* d_in, const int* in_sizes, int n_in,
                              void* d_out, int out_size, void* d_ws, size_t ws_size,
                              hipStream_t stream) {
    const float* depot = (const float*)d_in[0];
    const float* node  = (const float*)d_in[1];
    const float* dist  = (const float*)d_in[2];
    const float* log_scale = (const float*)d_in[3];
    const int*   flag  = (const int*)d_in[4];
    const float* Wd   = (const float*)d_in[5];
    const float* bd   = (const float*)d_in[6];
    const float* Wn   = (const float*)d_in[7];
    const float* bn   = (const float*)d_in[8];
    const float* Win  = (const float*)d_in[9];
    const float* bin_ = (const float*)d_in[10];
    const float* Wout = (const float*)d_in[11];
    const float* bout = (const float*)d_in[12];
    const float* Wq   = (const float*)d_in[13];
    const float* Wk   = (const float*)d_in[14];
    const float* Wv   = (const float*)d_in[15];
    const float* alpha= (const float*)d_in[16];
    const float* g1   = (const float*)d_in[17];
    const float* b1   = (const float*)d_in[18];
    const float* W1   = (const float*)d_in[19];
    const float* bW1  = (const float*)d_in[20];
    const float* W2   = (const float*)d_in[21];
    const float* bW2  = (const float*)d_in[22];
    const float* g2   = (const float*)d_in[23];
    const float* b2   = (const float*)d_in[24];

    float* ws = (float*)d_ws;
    size_t nxd = (size_t)B * S * D;                       // 4,096,000
    float* ya    = ws;
    float* yb    = ws + nxd;
    float* part1 = ws + 2 * nxd;                          // B*16*256 = 131072
    float* part2 = part1 + 131072;
    float* accb2 = part2 + 131072;                        // B*256
    unsigned short* sqb = (unsigned short*)(accb2 + 8192);          // B*S*D bf16
    unsigned short* mT  = sqb + nxd;                                // B*16*256*64
    unsigned short* wbf = mT + (size_t)B * 16 * 256 * 64;           // L*WSTR
    unsigned short* nd  = wbf + (size_t)L * WSTR;                   // B*1000*1024

    k_wprep<<<dim3(88, 6), 256, 0, stream>>>(Wq, Wk, Wv, W1, W2, wbf);
    k_prep<<<B * S, 256, 0, stream>>>(dist, nd);
    k_embed<<<B * S, 128, 0, stream>>>(depot, node, Wd, bd, Wn, bn, yb);
    k_rowxform<<<B, 128, 0, stream>>>(yb, Win, bin_, flag, 0);
    k_rowxform<<<B, 128, 0, stream>>>(yb, Wout, bout, flag, 1);

    for (int l = 0; l < L; l++) {
        int hasnorm = (l > 0) ? 1 : 0;
        const float* gpn = g2 + (l > 0 ? (l - 1) : 0) * D;
        const float* bpn = b2 + (l > 0 ? (l - 1) : 0) * D;
        const unsigned short* wl = wbf + (size_t)l * WSTR;
        k_qkv<<<B * 16, 256, 0, stream>>>(yb, part2, hasnorm, gpn, bpn, wl, sqb, mT);
        k_attn<<<B * 16, 512, 0, stream>>>(yb, part2, hasnorm, gpn, bpn,
                                           sqb, mT, nd, log_scale, alpha, l, ya, part1);
        k_ffn<<<B * 16, 256, 0, stream>>>(ya, part1, g1 + l * D, b1 + l * D,
                                          wl + 49152, wl + 114688,
                                          bW1 + (size_t)l * F, bW2 + (size_t)l * D, yb, part2);
    }
    k_finalize<<<32, 256, 0, stream>>>(part2, accb2);
    k_norm<<<B * S * D / 256, 256, 0, stream>>>(yb, accb2, g2 + 5 * D, b2 + 5 * D, (float*)d_out);
}